// Round 1
// baseline (1024.686 us; speedup 1.0000x reference)
//
#include <hip/hip_runtime.h>
#include <float.h>

// Problem constants
#define C_B     2
#define C_NQ    2048
#define C_NK    2048
#define C_QD    1024
#define C_CD    768
#define C_H     16
#define C_DH    64
#define C_INNER 1024   // H*DH

// ---------------- GEMM: C[M][N] = A[M][K] * B[N][K]^T (+ bias[N]) ----------------
// 64x64 tile, BK=16, 256 threads, each thread computes a 4x4 micro-tile.
#define BM 64
#define BN 64
#define BKK 16

__global__ __launch_bounds__(256) void gemm_nt(const float* __restrict__ A,
                                               const float* __restrict__ B,
                                               const float* __restrict__ bias,
                                               float* __restrict__ C,
                                               int M, int N, int K) {
  __shared__ float As[BKK][BM];   // k-major; row = 64 f32 (256B, 16B-aligned rows)
  __shared__ float Bs[BKK][BN];

  const int t  = threadIdx.x;
  const int tx = t % 16;
  const int ty = t / 16;
  const int m0 = blockIdx.y * BM;
  const int n0 = blockIdx.x * BN;

  // loader: thread t loads 4 consecutive k's of one row (A and B tiles)
  const int lm = t / 4;          // 0..63 row in tile
  const int lk = (t % 4) * 4;    // 0,4,8,12

  float acc[4][4] = {};

  for (int k0 = 0; k0 < K; k0 += BKK) {
    float4 a4 = *(const float4*)&A[(size_t)(m0 + lm) * K + k0 + lk];
    float4 b4 = *(const float4*)&B[(size_t)(n0 + lm) * K + k0 + lk];
    As[lk + 0][lm] = a4.x; As[lk + 1][lm] = a4.y;
    As[lk + 2][lm] = a4.z; As[lk + 3][lm] = a4.w;
    Bs[lk + 0][lm] = b4.x; Bs[lk + 1][lm] = b4.y;
    Bs[lk + 2][lm] = b4.z; Bs[lk + 3][lm] = b4.w;
    __syncthreads();

#pragma unroll
    for (int kk = 0; kk < BKK; ++kk) {
      float4 a = *(const float4*)&As[kk][ty * 4];
      float4 b = *(const float4*)&Bs[kk][tx * 4];
      float av[4] = {a.x, a.y, a.z, a.w};
      float bv[4] = {b.x, b.y, b.z, b.w};
#pragma unroll
      for (int i = 0; i < 4; ++i)
#pragma unroll
        for (int j = 0; j < 4; ++j)
          acc[i][j] += av[i] * bv[j];
    }
    __syncthreads();
  }

#pragma unroll
  for (int i = 0; i < 4; ++i) {
    const int m = m0 + ty * 4 + i;
#pragma unroll
    for (int j = 0; j < 4; ++j) {
      const int n = n0 + tx * 4 + j;
      float v = acc[i][j];
      if (bias) v += bias[n];
      C[(size_t)m * N + n] = v;
    }
  }
}

// ---------------- Flash-style cross attention (f32) ----------------
// One block = (b, h, 64 q-rows). Loop over NK in 64-row tiles.
// K tile stored transposed in LDS (Kt[d][j]) so score inner loop reads
// conflict-free float4s across j.
#define QB 64
#define KB 64
#define SSTR 68   // padded stride: 68 f32 = 272 B = 17*16 B (float4-aligned rows)

__global__ __launch_bounds__(256) void attn_fwd(const float* __restrict__ Q,
                                                const float* __restrict__ Km,
                                                const float* __restrict__ Vm,
                                                const int* __restrict__ mask,
                                                float* __restrict__ AO) {
  __shared__ float Qs[QB][SSTR];
  __shared__ float Kt[C_DH][SSTR];   // transposed: Kt[d][j]
  __shared__ float Vs[KB][SSTR];
  __shared__ float Ss[QB][SSTR];
  __shared__ float rowm[QB], rowl[QB], rowf[QB];

  const int bid = blockIdx.x;
  const int qt = bid & 31;           // NQ/QB = 32
  const int h  = (bid >> 5) & 15;    // H = 16
  const int b  = bid >> 9;
  const int q0 = qt * QB;

  const int t  = threadIdx.x;
  const int tx = t % 16;
  const int ty = t / 16;

  // Load Q tile: rows q0..q0+63, cols h*64..h*64+63
  {
    const int r  = t / 4;
    const int c0 = (t % 4) * 16;
    const float* src = &Q[((size_t)(b * C_NQ + q0 + r)) * C_INNER + h * C_DH + c0];
#pragma unroll
    for (int u = 0; u < 4; ++u)
      *(float4*)&Qs[r][c0 + u * 4] = *(const float4*)&src[u * 4];
  }
  if (t < QB) { rowm[t] = -FLT_MAX; rowl[t] = 0.f; }

  float acc[4][4] = {};   // O[i=ty*4+ii][d=tx*4+dd]
  const float scale = 0.125f;  // DH^-0.5
  __syncthreads();

  for (int k0 = 0; k0 < C_NK; k0 += KB) {
    // Load K (transposed) and V tiles
    {
      const int r  = t / 4;
      const int c0 = (t % 4) * 16;
      const float* ks = &Km[((size_t)(b * C_NK + k0 + r)) * C_INNER + h * C_DH + c0];
      const float* vs = &Vm[((size_t)(b * C_NK + k0 + r)) * C_INNER + h * C_DH + c0];
#pragma unroll
      for (int u = 0; u < 4; ++u) {
        float4 kv = *(const float4*)&ks[u * 4];
        Kt[c0 + u * 4 + 0][r] = kv.x;
        Kt[c0 + u * 4 + 1][r] = kv.y;
        Kt[c0 + u * 4 + 2][r] = kv.z;
        Kt[c0 + u * 4 + 3][r] = kv.w;
        *(float4*)&Vs[r][c0 + u * 4] = *(const float4*)&vs[u * 4];
      }
    }
    __syncthreads();

    // Scores S[i][j] = dot(Q[i], K[j]) over d
    float s[4][4] = {};
#pragma unroll
    for (int d4 = 0; d4 < C_DH; d4 += 4) {
      float qa[4][4];  // [ii][dd]
      float ka[4][4];  // [dd][jj]
#pragma unroll
      for (int ii = 0; ii < 4; ++ii) {
        float4 q4 = *(const float4*)&Qs[ty * 4 + ii][d4];
        qa[ii][0] = q4.x; qa[ii][1] = q4.y; qa[ii][2] = q4.z; qa[ii][3] = q4.w;
      }
#pragma unroll
      for (int dd = 0; dd < 4; ++dd) {
        float4 k4 = *(const float4*)&Kt[d4 + dd][tx * 4];
        ka[dd][0] = k4.x; ka[dd][1] = k4.y; ka[dd][2] = k4.z; ka[dd][3] = k4.w;
      }
#pragma unroll
      for (int ii = 0; ii < 4; ++ii)
#pragma unroll
        for (int jj = 0; jj < 4; ++jj)
#pragma unroll
          for (int dd = 0; dd < 4; ++dd)
            s[ii][jj] += qa[ii][dd] * ka[dd][jj];
    }

    // scale + additive mask bias, write to Ss
#pragma unroll
    for (int ii = 0; ii < 4; ++ii) {
      const int i = ty * 4 + ii;
      const int4 mv = *(const int4*)&mask[((size_t)b * C_NQ + q0 + i) * C_NK + k0 + tx * 4];
      const int mm[4] = {mv.x, mv.y, mv.z, mv.w};
#pragma unroll
      for (int jj = 0; jj < 4; ++jj) {
        float v = s[ii][jj] * scale + (mm[jj] ? 0.f : -(FLT_MAX * 0.5f));
        Ss[i][tx * 4 + jj] = v;
      }
    }
    __syncthreads();

    // Online softmax update (64 worker threads, one row each)
    if (t < QB) {
      const float m_old = rowm[t];
      float mx = m_old;
      for (int j = 0; j < KB; ++j) mx = fmaxf(mx, Ss[t][j]);
      const float f = __expf(m_old - mx);
      float l = rowl[t] * f;
      for (int j = 0; j < KB; ++j) {
        const float p = __expf(Ss[t][j] - mx);
        Ss[t][j] = p;
        l += p;
      }
      rowl[t] = l; rowm[t] = mx; rowf[t] = f;
    }
    __syncthreads();

    // Rescale accumulator and accumulate PV
    float fr[4];
#pragma unroll
    for (int ii = 0; ii < 4; ++ii) fr[ii] = rowf[ty * 4 + ii];
#pragma unroll
    for (int ii = 0; ii < 4; ++ii)
#pragma unroll
      for (int dd = 0; dd < 4; ++dd)
        acc[ii][dd] *= fr[ii];

#pragma unroll
    for (int j4 = 0; j4 < KB / 4; ++j4) {
      float pa[4][4];  // [ii][jx]
      float va[4][4];  // [jx][dd]
#pragma unroll
      for (int ii = 0; ii < 4; ++ii) {
        float4 p4 = *(const float4*)&Ss[ty * 4 + ii][j4 * 4];
        pa[ii][0] = p4.x; pa[ii][1] = p4.y; pa[ii][2] = p4.z; pa[ii][3] = p4.w;
      }
#pragma unroll
      for (int jx = 0; jx < 4; ++jx) {
        float4 v4 = *(const float4*)&Vs[j4 * 4 + jx][tx * 4];
        va[jx][0] = v4.x; va[jx][1] = v4.y; va[jx][2] = v4.z; va[jx][3] = v4.w;
      }
#pragma unroll
      for (int ii = 0; ii < 4; ++ii)
#pragma unroll
        for (int dd = 0; dd < 4; ++dd)
#pragma unroll
          for (int jx = 0; jx < 4; ++jx)
            acc[ii][dd] += pa[ii][jx] * va[jx][dd];
    }
    __syncthreads();  // before next tile overwrites Kt/Vs/Ss
  }

  // Epilogue: normalize and store
#pragma unroll
  for (int ii = 0; ii < 4; ++ii) {
    const int i = ty * 4 + ii;
    const float inv = 1.0f / rowl[i];
#pragma unroll
    for (int dd = 0; dd < 4; ++dd) {
      AO[((size_t)(b * C_NQ + q0 + i)) * C_INNER + h * C_DH + tx * 4 + dd] =
          acc[ii][dd] * inv;
    }
  }
}

// ---------------- launch ----------------
extern "C" void kernel_launch(void* const* d_in, const int* in_sizes, int n_in,
                              void* d_out, int out_size, void* d_ws, size_t ws_size,
                              hipStream_t stream) {
  const float* x   = (const float*)d_in[0];
  const float* ctx = (const float*)d_in[1];
  const int*   msk = (const int*)d_in[2];
  const float* Wq  = (const float*)d_in[3];
  const float* Wk  = (const float*)d_in[4];
  const float* Wv  = (const float*)d_in[5];
  const float* Wo  = (const float*)d_in[6];
  const float* bo  = (const float*)d_in[7];
  float* out = (float*)d_out;

  const size_t MQ = (size_t)C_B * C_NQ;   // 4096
  float* Q  = (float*)d_ws;
  float* K  = Q + MQ * C_INNER;
  float* V  = K + MQ * C_INNER;
  float* AO = V + MQ * C_INNER;

  dim3 blk(256);
  // Q = x @ Wq^T : M=4096, N=1024, K=1024
  gemm_nt<<<dim3(C_INNER / BN, MQ / BM), blk, 0, stream>>>(x, Wq, nullptr, Q,
                                                           (int)MQ, C_INNER, C_QD);
  // K = ctx @ Wk^T : M=4096, N=1024, K=768
  gemm_nt<<<dim3(C_INNER / BN, MQ / BM), blk, 0, stream>>>(ctx, Wk, nullptr, K,
                                                           (int)MQ, C_INNER, C_CD);
  // V = ctx @ Wv^T
  gemm_nt<<<dim3(C_INNER / BN, MQ / BM), blk, 0, stream>>>(ctx, Wv, nullptr, V,
                                                           (int)MQ, C_INNER, C_CD);
  // attention: B*H*(NQ/QB) = 2*16*32 = 1024 blocks
  attn_fwd<<<dim3(C_B * C_H * (C_NQ / QB)), blk, 0, stream>>>(Q, K, V, msk, AO);
  // out = AO @ Wo^T + bo
  gemm_nt<<<dim3(C_QD / BN, MQ / BM), blk, 0, stream>>>(AO, Wo, bo, out,
                                                        (int)MQ, C_QD, C_INNER);
}

// Round 3
// 259.891 us; speedup vs baseline: 3.9427x; 3.9427x over previous
//
#include <hip/hip_runtime.h>
#include <float.h>
#include <stdint.h>

#define C_B     2
#define C_NQ    2048
#define C_NK    2048
#define C_QD    1024
#define C_CD    768
#define C_H     16
#define C_DH    64
#define C_INNER 1024

typedef __bf16 bf16;
typedef __attribute__((ext_vector_type(8))) __bf16 bf16x8;
typedef __attribute__((ext_vector_type(4))) __bf16 bf16x4;
typedef __attribute__((ext_vector_type(4))) float f32x4;

// ---- async global->LDS, 16B per lane. LDS ptr must be wave-uniform. ----
__device__ __forceinline__ void async_copy16(const bf16* g, bf16* l) {
  __builtin_amdgcn_global_load_lds(
      (const __attribute__((address_space(1))) void*)g,
      (__attribute__((address_space(3))) void*)l,
      16, 0, 0);
}

// ---------------- f32 -> bf16 convert ----------------
__global__ __launch_bounds__(256) void cvtk(const float* __restrict__ src,
                                            bf16* __restrict__ dst, int n) {
  const int stride = gridDim.x * blockDim.x;
  for (int i = blockIdx.x * blockDim.x + threadIdx.x; i * 4 < n; i += stride) {
    float4 f = *(const float4*)&src[i * 4];
    bf16x4 o = { (bf16)f.x, (bf16)f.y, (bf16)f.z, (bf16)f.w };
    *(bf16x4*)&dst[i * 4] = o;
  }
}

// ---------------- mask int32 -> bitmask (u64 per 64 keys) ----------------
__global__ __launch_bounds__(256) void pack_mask(const int* __restrict__ mask,
                                                 unsigned long long* __restrict__ mb,
                                                 int nwords) {
  const int wid  = (blockIdx.x * blockDim.x + threadIdx.x) >> 6;
  const int lane = threadIdx.x & 63;
  const int nw   = (gridDim.x * blockDim.x) >> 6;
  for (int w = wid; w < nwords; w += nw) {
    int v = mask[(size_t)w * 64 + lane];
    unsigned long long bb = __ballot(v != 0);
    if (lane == 0) mb[w] = bb;
  }
}

// ---------------- bf16 GEMM: C[M][N] = A[M][K] * W[N][K]^T (+bias) ----------------
// BM=64, BN=128, BK=32, 256 threads (4 waves 2x2), wave tile 32x64.
template <int OUTBF16, int HASBIAS>
__global__ __launch_bounds__(256) void gemm_bt(const bf16* __restrict__ A,
                                               const bf16* __restrict__ W,
                                               const float* __restrict__ bias,
                                               void* __restrict__ Cout,
                                               int M, int N, int K) {
  __shared__ __align__(16) bf16 As[64 * 32];
  __shared__ __align__(16) bf16 Bs[128 * 32];

  const int t = threadIdx.x;
  const int w = t >> 6, lane = t & 63;
  const int l15 = lane & 15, lg = lane >> 4;
  const int wm = w >> 1, wn = w & 1;
  const int m0 = blockIdx.y * 64, n0 = blockIdx.x * 128;

  f32x4 acc[2][4] = {};

  // staging: A = 4KB (1 call/wave), B = 8KB (2 calls/wave)
  const bf16* Ag  = A + (size_t)(m0 + w * 16 + (lane >> 2)) * K + (lane & 3) * 8;
  const bf16* Bg0 = W + (size_t)(n0 + w * 32 + (lane >> 2)) * K + (lane & 3) * 8;
  const bf16* Bg1 = W + (size_t)(n0 + w * 32 + 16 + (lane >> 2)) * K + (lane & 3) * 8;
  bf16* AsW  = As + w * 512;           // chunk base (w*64)*8 shorts
  bf16* BsW0 = Bs + w * 1024;          // (w*128)*8
  bf16* BsW1 = Bs + w * 1024 + 512;    // (w*128+64)*8

  for (int k0 = 0; k0 < K; k0 += 32) {
    async_copy16(Ag + k0, AsW);
    async_copy16(Bg0 + k0, BsW0);
    async_copy16(Bg1 + k0, BsW1);
    __syncthreads();

    bf16x8 af[2], bfv[4];
#pragma unroll
    for (int mi = 0; mi < 2; ++mi)
      af[mi] = *(const bf16x8*)&As[(wm * 32 + mi * 16 + l15) * 32 + lg * 8];
#pragma unroll
    for (int ni = 0; ni < 4; ++ni)
      bfv[ni] = *(const bf16x8*)&Bs[(wn * 64 + ni * 16 + l15) * 32 + lg * 8];
#pragma unroll
    for (int mi = 0; mi < 2; ++mi)
#pragma unroll
      for (int ni = 0; ni < 4; ++ni)
        acc[mi][ni] = __builtin_amdgcn_mfma_f32_16x16x32_bf16(af[mi], bfv[ni],
                                                              acc[mi][ni], 0, 0, 0);
    __syncthreads();
  }

#pragma unroll
  for (int mi = 0; mi < 2; ++mi)
#pragma unroll
    for (int ni = 0; ni < 4; ++ni)
#pragma unroll
      for (int r = 0; r < 4; ++r) {
        const int row = m0 + wm * 32 + mi * 16 + lg * 4 + r;
        const int col = n0 + wn * 64 + ni * 16 + l15;
        float v = acc[mi][ni][r];
        if (HASBIAS) v += bias[col];
        if (OUTBF16) ((bf16*)Cout)[(size_t)row * N + col] = (bf16)v;
        else         ((float*)Cout)[(size_t)row * N + col] = v;
      }
}

// ---------------- V transpose: V[b][k][h*64+d] -> Vt[b][h][d][k] ----------------
__global__ __launch_bounds__(256) void vtrans(const bf16* __restrict__ V,
                                              bf16* __restrict__ Vt) {
  __shared__ __align__(16) bf16 T[64][80];  // 160B rows (16B-aligned), bank step 8
  const int kt = blockIdx.x, h = blockIdx.y, b = blockIdx.z;
  const int t = threadIdx.x;
  {
    const int kl = t >> 2, db = (t & 3) * 16;
    const bf16* src = &V[((size_t)(b * C_NK + kt * 64 + kl)) * C_INNER + h * 64 + db];
    *(bf16x8*)&T[kl][db]     = *(const bf16x8*)&src[0];
    *(bf16x8*)&T[kl][db + 8] = *(const bf16x8*)&src[8];
  }
  __syncthreads();
  {
    const int d = t >> 2, kb = (t & 3) * 16;
    bf16x8 o0, o1;
#pragma unroll
    for (int j = 0; j < 8; ++j) { o0[j] = T[kb + j][d]; o1[j] = T[kb + 8 + j][d]; }
    bf16* dst = &Vt[((size_t)((b * C_H + h) * C_DH + d)) * C_NK + kt * 64 + kb];
    *(bf16x8*)&dst[0] = o0;
    *(bf16x8*)&dst[8] = o1;
  }
}

// ---------------- Flash cross-attention, bf16 MFMA ----------------
// Block: 64 q-rows, 4 waves (16 rows each). K-tile = 64 keys.
// Ks/Vs staged via global_load_lds with pre-swizzled global source (chunk XOR).
__global__ __launch_bounds__(256) void attn_fwd(const bf16* __restrict__ Q,
                                                const bf16* __restrict__ K,
                                                const bf16* __restrict__ Vt,
                                                const unsigned long long* __restrict__ MB,
                                                bf16* __restrict__ AO) {
  __shared__ __align__(16) bf16 Ks[64 * 64];
  __shared__ __align__(16) bf16 Vs[64 * 64];
  __shared__ __align__(16) bf16 Ps[4 * 16 * 64];

  const int qt = blockIdx.x, h = blockIdx.y, b = blockIdx.z;
  const int q0 = qt * 64;
  const int t = threadIdx.x, w = t >> 6, lane = t & 63;
  const int l15 = lane & 15, lg = lane >> 4;

  // Q fragments in registers (wave w owns q rows q0+w*16 .. +15)
  bf16x8 qf[2];
  {
    const int qrow = q0 + w * 16 + l15;
    const bf16* qs = Q + ((size_t)(b * C_NQ + qrow)) * C_INNER + h * C_DH + lg * 8;
    qf[0] = *(const bf16x8*)&qs[0];
    qf[1] = *(const bf16x8*)&qs[32];
  }

  float m_run[4], l_run[4];
#pragma unroll
  for (int r = 0; r < 4; ++r) { m_run[r] = -3.0e38f; l_run[r] = 0.f; }
  f32x4 acc_o[4] = {};
  const float scale = 0.125f;

  for (int kt = 0; kt < C_NK / 64; ++kt) {
    const int k0 = kt * 64;
    // stage K and Vt tiles (8KB each): wave w covers chunks w*128 .. +127
#pragma unroll
    for (int c = 0; c < 2; ++c) {
      const int chunk = w * 128 + c * 64 + lane;
      const int row = chunk >> 3, pcb = chunk & 7;
      const int srcb = (pcb ^ (row & 7)) * 8;   // pre-swizzled source d/k block
      const bf16* kg = K + ((size_t)(b * C_NK + k0 + row)) * C_INNER + h * C_DH + srcb;
      async_copy16(kg, &Ks[(w * 128 + c * 64) * 8]);
      const bf16* vg = Vt + ((size_t)((b * C_H + h) * C_DH + row)) * C_NK + k0 + srcb;
      async_copy16(vg, &Vs[(w * 128 + c * 64) * 8]);
    }
    // mask bit-words (one u64 covers this tile's 64 keys) for this lane's 4 rows
    unsigned long long wd[4];
#pragma unroll
    for (int r = 0; r < 4; ++r)
      wd[r] = MB[((size_t)(b * C_NQ + q0 + w * 16 + lg * 4 + r)) * (C_NK / 64) + kt];
    __syncthreads();

    // S = Q K^T  (rows = lg*4+r, cols = ni*16+l15)
    f32x4 accs[4] = {};
#pragma unroll
    for (int ni = 0; ni < 4; ++ni)
#pragma unroll
      for (int ks = 0; ks < 2; ++ks) {
        const int row = ni * 16 + l15;
        const int lcb = ks * 4 + lg;
        bf16x8 kf = *(const bf16x8*)&Ks[row * 64 + ((lcb ^ (row & 7)) << 3)];
        accs[ni] = __builtin_amdgcn_mfma_f32_16x16x32_bf16(qf[ks], kf, accs[ni], 0, 0, 0);
      }

    // wave-parallel online softmax
    float sv[4][4], pm[4];
#pragma unroll
    for (int r = 0; r < 4; ++r) pm[r] = -3.0e38f;
#pragma unroll
    for (int ni = 0; ni < 4; ++ni)
#pragma unroll
      for (int r = 0; r < 4; ++r) {
        const unsigned ok = (unsigned)((wd[r] >> (ni * 16 + l15)) & 1ULL);
        const float v = accs[ni][r] * scale + (ok ? 0.f : -1.0e30f);
        sv[ni][r] = v;
        pm[r] = fmaxf(pm[r], v);
      }
#pragma unroll
    for (int off = 1; off < 16; off <<= 1)
#pragma unroll
      for (int r = 0; r < 4; ++r) pm[r] = fmaxf(pm[r], __shfl_xor(pm[r], off));

    float f[4], ps[4];
#pragma unroll
    for (int r = 0; r < 4; ++r) {
      const float mn = fmaxf(m_run[r], pm[r]);
      f[r] = __expf(m_run[r] - mn);
      m_run[r] = mn;
      ps[r] = 0.f;
    }
    // p = exp(s - m), accumulate row sums, write bf16 P to swizzled LDS strip
#pragma unroll
    for (int ni = 0; ni < 4; ++ni)
#pragma unroll
      for (int r = 0; r < 4; ++r) {
        const float p = __expf(sv[ni][r] - m_run[r]);
        ps[r] += p;
        const int prow = lg * 4 + r;
        const int col = ni * 16 + l15;
        Ps[(w * 16 + prow) * 64 + ((((col >> 3) ^ (prow & 7)) << 3) + (col & 7))] = (bf16)p;
      }
#pragma unroll
    for (int off = 1; off < 16; off <<= 1)
#pragma unroll
      for (int r = 0; r < 4; ++r) ps[r] += __shfl_xor(ps[r], off);
#pragma unroll
    for (int r = 0; r < 4; ++r) l_run[r] = l_run[r] * f[r] + ps[r];
#pragma unroll
    for (int di = 0; di < 4; ++di)
#pragma unroll
      for (int r = 0; r < 4; ++r) acc_o[di][r] *= f[r];

    __syncthreads();

    // O += P V  (A = own P strip, B = Vt tile)
#pragma unroll
    for (int ks = 0; ks < 2; ++ks) {
      const int arow = l15;
      const int lcb = ks * 4 + lg;
      bf16x8 pf = *(const bf16x8*)&Ps[(w * 16 + arow) * 64 + ((lcb ^ (arow & 7)) << 3)];
#pragma unroll
      for (int di = 0; di < 4; ++di) {
        const int vrow = di * 16 + l15;
        bf16x8 vf = *(const bf16x8*)&Vs[vrow * 64 + ((lcb ^ (vrow & 7)) << 3)];
        acc_o[di] = __builtin_amdgcn_mfma_f32_16x16x32_bf16(pf, vf, acc_o[di], 0, 0, 0);
      }
    }
    __syncthreads();
  }

  // epilogue: normalize, store bf16
#pragma unroll
  for (int r = 0; r < 4; ++r) {
    const float inv = 1.f / l_run[r];
    const int q = q0 + w * 16 + lg * 4 + r;
#pragma unroll
    for (int di = 0; di < 4; ++di)
      AO[((size_t)(b * C_NQ + q)) * C_INNER + h * C_DH + di * 16 + l15] =
          (bf16)(acc_o[di][r] * inv);
  }
}

// ---------------- launch ----------------
extern "C" void kernel_launch(void* const* d_in, const int* in_sizes, int n_in,
                              void* d_out, int out_size, void* d_ws, size_t ws_size,
                              hipStream_t stream) {
  const float* x   = (const float*)d_in[0];
  const float* ctx = (const float*)d_in[1];
  const int*   msk = (const int*)d_in[2];
  const float* Wq  = (const float*)d_in[3];
  const float* Wk  = (const float*)d_in[4];
  const float* Wv  = (const float*)d_in[5];
  const float* Wo  = (const float*)d_in[6];
  const float* bo  = (const float*)d_in[7];
  float* out = (float*)d_out;

  // workspace layout (bf16 elems). Vtb ALIASES xb (x dead after Q proj;
  // same-stream ordering serializes). Total ~54 MB < proven 64 MB bound.
  bf16* ws  = (bf16*)d_ws;
  bf16* xb  = ws;                   // 4,194,304
  bf16* cb  = xb  + 4194304;        // 3,145,728
  bf16* wqb = cb  + 3145728;        // 1,048,576
  bf16* wkb = wqb + 1048576;        //   786,432
  bf16* wvb = wkb + 786432;         //   786,432
  bf16* wob = wvb + 786432;         // 1,048,576
  bf16* Qb  = wob + 1048576;        // 4,194,304
  bf16* Kb  = Qb  + 4194304;        // 4,194,304
  bf16* Vb  = Kb  + 4194304;        // 4,194,304
  bf16* AOb = Vb  + 4194304;        // 4,194,304
  unsigned long long* mb = (unsigned long long*)(AOb + 4194304);  // 131072 u64
  bf16* Vtb = xb;                   // alias

  dim3 blk(256);
  auto cvt = [&](const float* s, bf16* d, int n) {
    int blocks = (n / 4 + 255) / 256;
    if (blocks > 2048) blocks = 2048;
    cvtk<<<blocks, blk, 0, stream>>>(s, d, n);
  };
  cvt(x,   xb,  C_B * C_NQ * C_QD);
  cvt(ctx, cb,  C_B * C_NK * C_CD);
  cvt(Wq,  wqb, C_INNER * C_QD);
  cvt(Wk,  wkb, C_INNER * C_CD);
  cvt(Wv,  wvb, C_INNER * C_CD);
  cvt(Wo,  wob, C_QD * C_INNER);

  pack_mask<<<512, blk, 0, stream>>>(msk, mb, C_B * C_NQ * (C_NK / 64));

  const int MQ = C_B * C_NQ;  // 4096
  gemm_bt<1, 0><<<dim3(C_INNER / 128, MQ / 64), blk, 0, stream>>>(xb, wqb, nullptr, Qb, MQ, C_INNER, C_QD);
  gemm_bt<1, 0><<<dim3(C_INNER / 128, MQ / 64), blk, 0, stream>>>(cb, wkb, nullptr, Kb, MQ, C_INNER, C_CD);
  gemm_bt<1, 0><<<dim3(C_INNER / 128, MQ / 64), blk, 0, stream>>>(cb, wvb, nullptr, Vb, MQ, C_INNER, C_CD);

  vtrans<<<dim3(C_NK / 64, C_H, C_B), blk, 0, stream>>>(Vb, Vtb);

  attn_fwd<<<dim3(C_NQ / 64, C_H, C_B), blk, 0, stream>>>(Qb, Kb, Vtb, mb, AOb);

  // out = AO @ Wo^T + bo (f32 out)
  gemm_bt<0, 1><<<dim3(C_QD / 128, MQ / 64), blk, 0, stream>>>(AOb, wob, bo, out, MQ, C_QD, C_INNER);
}

// Round 4
// 237.421 us; speedup vs baseline: 4.3159x; 1.0946x over previous
//
#include <hip/hip_runtime.h>
#include <float.h>
#include <stdint.h>

#define C_B     2
#define C_NQ    2048
#define C_NK    2048
#define C_QD    1024
#define C_CD    768
#define C_H     16
#define C_DH    64
#define C_INNER 1024

typedef __bf16 bf16;
typedef __attribute__((ext_vector_type(8))) __bf16 bf16x8;
typedef __attribute__((ext_vector_type(4))) __bf16 bf16x4;
typedef __attribute__((ext_vector_type(4))) float f32x4;

#if __has_builtin(__builtin_amdgcn_exp2f)
#define EXP2(x) __builtin_amdgcn_exp2f(x)
#else
#define EXP2(x) __expf((x) * 0.69314718056f)
#endif

// DPP rotate-reduce within each 16-lane row (pure VALU, no ds_swizzle).
__device__ __forceinline__ float dppmax16(float x) {
  x = fmaxf(x, __int_as_float(__builtin_amdgcn_mov_dpp(__float_as_int(x), 0x128, 0xF, 0xF, true)));
  x = fmaxf(x, __int_as_float(__builtin_amdgcn_mov_dpp(__float_as_int(x), 0x124, 0xF, 0xF, true)));
  x = fmaxf(x, __int_as_float(__builtin_amdgcn_mov_dpp(__float_as_int(x), 0x122, 0xF, 0xF, true)));
  x = fmaxf(x, __int_as_float(__builtin_amdgcn_mov_dpp(__float_as_int(x), 0x121, 0xF, 0xF, true)));
  return x;
}
__device__ __forceinline__ float dppadd16(float x) {
  x += __int_as_float(__builtin_amdgcn_mov_dpp(__float_as_int(x), 0x128, 0xF, 0xF, true));
  x += __int_as_float(__builtin_amdgcn_mov_dpp(__float_as_int(x), 0x124, 0xF, 0xF, true));
  x += __int_as_float(__builtin_amdgcn_mov_dpp(__float_as_int(x), 0x122, 0xF, 0xF, true));
  x += __int_as_float(__builtin_amdgcn_mov_dpp(__float_as_int(x), 0x121, 0xF, 0xF, true));
  return x;
}

// ---- async global->LDS, 16B per lane. LDS dest is wave-uniform base + lane*16. ----
__device__ __forceinline__ void async_copy16(const bf16* g, bf16* l) {
  __builtin_amdgcn_global_load_lds(
      (const __attribute__((address_space(1))) void*)g,
      (__attribute__((address_space(3))) void*)l,
      16, 0, 0);
}

// ---------------- f32 -> bf16 convert ----------------
__global__ __launch_bounds__(256) void cvtk(const float* __restrict__ src,
                                            bf16* __restrict__ dst, int n) {
  const int stride = gridDim.x * blockDim.x;
  for (int i = blockIdx.x * blockDim.x + threadIdx.x; i * 4 < n; i += stride) {
    float4 f = *(const float4*)&src[i * 4];
    bf16x4 o = { (bf16)f.x, (bf16)f.y, (bf16)f.z, (bf16)f.w };
    *(bf16x4*)&dst[i * 4] = o;
  }
}

// ---------------- mask int32 -> bitmask (u64 per 64 keys) ----------------
__global__ __launch_bounds__(256) void pack_mask(const int* __restrict__ mask,
                                                 unsigned long long* __restrict__ mb,
                                                 int nwords) {
  const int wid  = (blockIdx.x * blockDim.x + threadIdx.x) >> 6;
  const int lane = threadIdx.x & 63;
  const int nw   = (gridDim.x * blockDim.x) >> 6;
  for (int w = wid; w < nwords; w += nw) {
    int v = mask[(size_t)w * 64 + lane];
    unsigned long long bb = __ballot(v != 0);
    if (lane == 0) mb[w] = bb;
  }
}

// ---------------- bf16 GEMM: C = A * W^T (+bias) * oscale ----------------
// BM=64, BN=128, BK=32, 256 threads (4 waves 2x2), 2-phase double-buffered LDS.
template <int OUTBF16, int HASBIAS>
__global__ __launch_bounds__(256) void gemm_bt(const bf16* __restrict__ A,
                                               const bf16* __restrict__ W,
                                               const float* __restrict__ bias,
                                               void* __restrict__ Cout,
                                               int M, int N, int K, float oscale) {
  __shared__ __align__(16) bf16 As[2][64 * 32];
  __shared__ __align__(16) bf16 Bs[2][128 * 32];

  const int t = threadIdx.x;
  const int w = t >> 6, lane = t & 63;
  const int l15 = lane & 15, lg = lane >> 4;
  const int wm = w >> 1, wn = w & 1;
  const int m0 = blockIdx.y * 64, n0 = blockIdx.x * 128;

  f32x4 acc[2][4] = {};

  const bf16* Ag  = A + (size_t)(m0 + w * 16 + (lane >> 2)) * K + (lane & 3) * 8;
  const bf16* Bg0 = W + (size_t)(n0 + w * 32 + (lane >> 2)) * K + (lane & 3) * 8;
  const bf16* Bg1 = W + (size_t)(n0 + w * 32 + 16 + (lane >> 2)) * K + (lane & 3) * 8;

  auto stage = [&](int nb, int k0) {
    async_copy16(Ag + k0, &As[nb][w * 512]);
    async_copy16(Bg0 + k0, &Bs[nb][w * 1024]);
    async_copy16(Bg1 + k0, &Bs[nb][w * 1024 + 512]);
  };

  stage(0, 0);
  int cur = 0;
  for (int k0 = 0; k0 < K; k0 += 32) {
    __syncthreads();                 // buf[cur] staged; prev reads done
    if (k0 + 32 < K) stage(cur ^ 1, k0 + 32);

    bf16x8 af[2], bfv[4];
#pragma unroll
    for (int mi = 0; mi < 2; ++mi)
      af[mi] = *(const bf16x8*)&As[cur][(wm * 32 + mi * 16 + l15) * 32 + lg * 8];
#pragma unroll
    for (int ni = 0; ni < 4; ++ni)
      bfv[ni] = *(const bf16x8*)&Bs[cur][(wn * 64 + ni * 16 + l15) * 32 + lg * 8];
#pragma unroll
    for (int mi = 0; mi < 2; ++mi)
#pragma unroll
      for (int ni = 0; ni < 4; ++ni)
        acc[mi][ni] = __builtin_amdgcn_mfma_f32_16x16x32_bf16(af[mi], bfv[ni],
                                                              acc[mi][ni], 0, 0, 0);
    cur ^= 1;
  }

#pragma unroll
  for (int mi = 0; mi < 2; ++mi)
#pragma unroll
    for (int ni = 0; ni < 4; ++ni)
#pragma unroll
      for (int r = 0; r < 4; ++r) {
        const int row = m0 + wm * 32 + mi * 16 + lg * 4 + r;
        const int col = n0 + wn * 64 + ni * 16 + l15;
        float v = acc[mi][ni][r] * oscale;
        if (HASBIAS) v += bias[col];
        if (OUTBF16) ((bf16*)Cout)[(size_t)row * N + col] = (bf16)v;
        else         ((float*)Cout)[(size_t)row * N + col] = v;
      }
}

// ---------------- V transpose: V[b][k][h*64+d] -> Vt[b][h][d][k] ----------------
__global__ __launch_bounds__(256) void vtrans(const bf16* __restrict__ V,
                                              bf16* __restrict__ Vt) {
  __shared__ __align__(16) bf16 T[64][80];
  const int kt = blockIdx.x, h = blockIdx.y, b = blockIdx.z;
  const int t = threadIdx.x;
  {
    const int kl = t >> 2, db = (t & 3) * 16;
    const bf16* src = &V[((size_t)(b * C_NK + kt * 64 + kl)) * C_INNER + h * 64 + db];
    *(bf16x8*)&T[kl][db]     = *(const bf16x8*)&src[0];
    *(bf16x8*)&T[kl][db + 8] = *(const bf16x8*)&src[8];
  }
  __syncthreads();
  {
    const int d = t >> 2, kb = (t & 3) * 16;
    bf16x8 o0, o1;
#pragma unroll
    for (int j = 0; j < 8; ++j) { o0[j] = T[kb + j][d]; o1[j] = T[kb + 8 + j][d]; }
    bf16* dst = &Vt[((size_t)((b * C_H + h) * C_DH + d)) * C_NK + kt * 64 + kb];
    *(bf16x8*)&dst[0] = o0;
    *(bf16x8*)&dst[8] = o1;
  }
}

// ---------------- Flash cross-attention, bf16 MFMA, 2-phase dbuf ----------------
// Q is PRE-SCALED by 0.125*log2(e) in its GEMM epilogue; softmax in exp2 domain.
__global__ __launch_bounds__(256) void attn_fwd(const bf16* __restrict__ Q,
                                                const bf16* __restrict__ K,
                                                const bf16* __restrict__ Vt,
                                                const unsigned long long* __restrict__ MB,
                                                bf16* __restrict__ AO) {
  __shared__ __align__(16) bf16 Ks[2][64 * 64];
  __shared__ __align__(16) bf16 Vs[2][64 * 64];
  __shared__ __align__(16) bf16 Ps[4 * 16 * 64];

  const int qt = blockIdx.x, h = blockIdx.y, b = blockIdx.z;
  const int q0 = qt * 64;
  const int t = threadIdx.x, w = t >> 6, lane = t & 63;
  const int l15 = lane & 15, lg = lane >> 4;

  bf16x8 qf[2];
  {
    const int qrow = q0 + w * 16 + l15;
    const bf16* qs = Q + ((size_t)(b * C_NQ + qrow)) * C_INNER + h * C_DH + lg * 8;
    qf[0] = *(const bf16x8*)&qs[0];
    qf[1] = *(const bf16x8*)&qs[32];
  }

  float m_run[4], l_run[4];
#pragma unroll
  for (int r = 0; r < 4; ++r) { m_run[r] = -3.0e38f; l_run[r] = 0.f; }
  f32x4 acc_o[4] = {};

  auto stage = [&](int nb, int kt) {
#pragma unroll
    for (int c = 0; c < 2; ++c) {
      const int chunk = w * 128 + c * 64 + lane;
      const int row = chunk >> 3, pcb = chunk & 7;
      const int srcb = (pcb ^ (row & 7)) * 8;      // pre-swizzled global source
      const bf16* kg = K + ((size_t)(b * C_NK + kt * 64 + row)) * C_INNER + h * C_DH + srcb;
      async_copy16(kg, &Ks[nb][(w * 128 + c * 64) * 8]);
      const bf16* vg = Vt + ((size_t)((b * C_H + h) * C_DH + row)) * C_NK + kt * 64 + srcb;
      async_copy16(vg, &Vs[nb][(w * 128 + c * 64) * 8]);
    }
  };

  stage(0, 0);
  int cur = 0;

  for (int kt = 0; kt < C_NK / 64; ++kt) {
    // mask words first (older vmem ops than next stage -> no vmcnt(0) stall)
    unsigned long long wd[4];
#pragma unroll
    for (int r = 0; r < 4; ++r)
      wd[r] = MB[((size_t)(b * C_NQ + q0 + w * 16 + lg * 4 + r)) * (C_NK / 64) + kt];

    __syncthreads();                 // buf[cur] ready; prev tile reads done
    if (kt + 1 < C_NK / 64) stage(cur ^ 1, kt + 1);

    // S = Q K^T (exp2 domain, Q pre-scaled)
    f32x4 accs[4] = {};
#pragma unroll
    for (int ni = 0; ni < 4; ++ni)
#pragma unroll
      for (int ks = 0; ks < 2; ++ks) {
        const int row = ni * 16 + l15;
        const int lcb = ks * 4 + lg;
        bf16x8 kf = *(const bf16x8*)&Ks[cur][row * 64 + ((lcb ^ (row & 7)) << 3)];
        accs[ni] = __builtin_amdgcn_mfma_f32_16x16x32_bf16(qf[ks], kf, accs[ni], 0, 0, 0);
      }

    float f[4];
#pragma unroll
    for (int r = 0; r < 4; ++r) {
      const unsigned long long sh = wd[r] >> l15;
      const unsigned lo = (unsigned)sh, hi = (unsigned)(sh >> 32);
      const unsigned bit[4] = { lo & 1u, (lo >> 16) & 1u, hi & 1u, (hi >> 16) & 1u };
      float pm = -1.0e30f;
#pragma unroll
      for (int ni = 0; ni < 4; ++ni) {
        const float v = bit[ni] ? accs[ni][r] : -1.0e30f;
        accs[ni][r] = v;
        pm = fmaxf(pm, v);
      }
      pm = dppmax16(pm);
      const float mn = fmaxf(m_run[r], pm);
      f[r] = EXP2(m_run[r] - mn);
      m_run[r] = mn;
      float ps = 0.f;
      const int prow = lg * 4 + r;
#pragma unroll
      for (int ni = 0; ni < 4; ++ni) {
        const float p = EXP2(accs[ni][r] - mn);
        ps += p;
        const int col = ni * 16 + l15;
        Ps[(w * 16 + prow) * 64 + ((((col >> 3) ^ (prow & 7)) << 3) + (col & 7))] = (bf16)p;
      }
      ps = dppadd16(ps);
      l_run[r] = l_run[r] * f[r] + ps;
    }
#pragma unroll
    for (int di = 0; di < 4; ++di)
#pragma unroll
      for (int r = 0; r < 4; ++r) acc_o[di][r] *= f[r];

    // O += P V (own P strip written by this wave; same-wave DS ops are ordered)
#pragma unroll
    for (int ks = 0; ks < 2; ++ks) {
      const int arow = l15;
      const int lcb = ks * 4 + lg;
      bf16x8 pf = *(const bf16x8*)&Ps[(w * 16 + arow) * 64 + ((lcb ^ (arow & 7)) << 3)];
#pragma unroll
      for (int di = 0; di < 4; ++di) {
        const int vrow = di * 16 + l15;
        bf16x8 vf = *(const bf16x8*)&Vs[cur][vrow * 64 + ((lcb ^ (vrow & 7)) << 3)];
        acc_o[di] = __builtin_amdgcn_mfma_f32_16x16x32_bf16(pf, vf, acc_o[di], 0, 0, 0);
      }
    }
    cur ^= 1;
  }

#pragma unroll
  for (int r = 0; r < 4; ++r) {
    const float inv = 1.f / l_run[r];
    const int q = q0 + w * 16 + lg * 4 + r;
#pragma unroll
    for (int di = 0; di < 4; ++di)
      AO[((size_t)(b * C_NQ + q)) * C_INNER + h * C_DH + di * 16 + l15] =
          (bf16)(acc_o[di][r] * inv);
  }
}

// ---------------- launch ----------------
extern "C" void kernel_launch(void* const* d_in, const int* in_sizes, int n_in,
                              void* d_out, int out_size, void* d_ws, size_t ws_size,
                              hipStream_t stream) {
  const float* x   = (const float*)d_in[0];
  const float* ctx = (const float*)d_in[1];
  const int*   msk = (const int*)d_in[2];
  const float* Wq  = (const float*)d_in[3];
  const float* Wk  = (const float*)d_in[4];
  const float* Wv  = (const float*)d_in[5];
  const float* Wo  = (const float*)d_in[6];
  const float* bo  = (const float*)d_in[7];
  float* out = (float*)d_out;

  // workspace layout (bf16 elems). Vtb ALIASES xb (x dead after Q proj).
  bf16* ws  = (bf16*)d_ws;
  bf16* xb  = ws;                   // 4,194,304
  bf16* cb  = xb  + 4194304;        // 3,145,728
  bf16* wqb = cb  + 3145728;        // 1,048,576
  bf16* wkb = wqb + 1048576;        //   786,432
  bf16* wvb = wkb + 786432;         //   786,432
  bf16* wob = wvb + 786432;         // 1,048,576
  bf16* Qb  = wob + 1048576;        // 4,194,304
  bf16* Kb  = Qb  + 4194304;
  bf16* Vb  = Kb  + 4194304;
  bf16* AOb = Vb  + 4194304;
  unsigned long long* mb = (unsigned long long*)(AOb + 4194304);
  bf16* Vtb = xb;                   // alias

  dim3 blk(256);
  auto cvt = [&](const float* s, bf16* d, int n) {
    int blocks = (n / 4 + 255) / 256;
    if (blocks > 2048) blocks = 2048;
    cvtk<<<blocks, blk, 0, stream>>>(s, d, n);
  };
  cvt(x,   xb,  C_B * C_NQ * C_QD);
  cvt(ctx, cb,  C_B * C_NK * C_CD);
  cvt(Wq,  wqb, C_INNER * C_QD);
  cvt(Wk,  wkb, C_INNER * C_CD);
  cvt(Wv,  wvb, C_INNER * C_CD);
  cvt(Wo,  wob, C_QD * C_INNER);

  pack_mask<<<512, blk, 0, stream>>>(msk, mb, C_B * C_NQ * (C_NK / 64));

  const int MQ = C_B * C_NQ;  // 4096
  const float qscale = 0.125f * 1.44269504f;  // DH^-0.5 * log2(e), folded into Q
  gemm_bt<1, 0><<<dim3(C_INNER / 128, MQ / 64), blk, 0, stream>>>(xb, wqb, nullptr, Qb, MQ, C_INNER, C_QD, qscale);
  gemm_bt<1, 0><<<dim3(C_INNER / 128, MQ / 64), blk, 0, stream>>>(cb, wkb, nullptr, Kb, MQ, C_INNER, C_CD, 1.0f);
  gemm_bt<1, 0><<<dim3(C_INNER / 128, MQ / 64), blk, 0, stream>>>(cb, wvb, nullptr, Vb, MQ, C_INNER, C_CD, 1.0f);

  vtrans<<<dim3(C_NK / 64, C_H, C_B), blk, 0, stream>>>(Vb, Vtb);

  attn_fwd<<<dim3(C_NQ / 64, C_H, C_B), blk, 0, stream>>>(Qb, Kb, Vtb, mb, AOb);

  gemm_bt<0, 1><<<dim3(C_QD / 128, MQ / 64), blk, 0, stream>>>(AOb, wob, bo, out, MQ, C_QD, C_INNER, 1.0f);
}

// Round 6
// 196.492 us; speedup vs baseline: 5.2149x; 1.2083x over previous
//
#include <hip/hip_runtime.h>
#include <float.h>
#include <stdint.h>

#define C_B     2
#define C_NQ    2048
#define C_NK    2048
#define C_QD    1024
#define C_CD    768
#define C_H     16
#define C_DH    64
#define C_INNER 1024

typedef __bf16 bf16;
typedef __attribute__((ext_vector_type(8))) __bf16 bf16x8;
typedef __attribute__((ext_vector_type(4))) __bf16 bf16x4;
typedef __attribute__((ext_vector_type(4))) float f32x4;
typedef __attribute__((ext_vector_type(16))) float f32x16;

#if __has_builtin(__builtin_amdgcn_exp2f)
#define EXP2(x) __builtin_amdgcn_exp2f(x)
#else
#define EXP2(x) __expf((x) * 0.69314718056f)
#endif

// ---- async global->LDS, 16B per lane. LDS dest is wave-uniform base + lane*16. ----
__device__ __forceinline__ void async_copy16(const bf16* g, bf16* l) {
  __builtin_amdgcn_global_load_lds(
      (const __attribute__((address_space(1))) void*)g,
      (__attribute__((address_space(3))) void*)l,
      16, 0, 0);
}

// ---------------- f32 -> bf16 convert ----------------
__global__ __launch_bounds__(256) void cvtk(const float* __restrict__ src,
                                            bf16* __restrict__ dst, int n) {
  const int stride = gridDim.x * blockDim.x;
  for (int i = blockIdx.x * blockDim.x + threadIdx.x; i * 4 < n; i += stride) {
    float4 f = *(const float4*)&src[i * 4];
    bf16x4 o = { (bf16)f.x, (bf16)f.y, (bf16)f.z, (bf16)f.w };
    *(bf16x4*)&dst[i * 4] = o;
  }
}

// ---------------- mask int32 -> bitmask (u64 per 64 keys) ----------------
__global__ __launch_bounds__(256) void pack_mask(const int* __restrict__ mask,
                                                 unsigned long long* __restrict__ mb,
                                                 int nwords) {
  const int wid  = (blockIdx.x * blockDim.x + threadIdx.x) >> 6;
  const int lane = threadIdx.x & 63;
  const int nw   = (gridDim.x * blockDim.x) >> 6;
  for (int w = wid; w < nwords; w += nw) {
    int v = mask[(size_t)w * 64 + lane];
    unsigned long long bb = __ballot(v != 0);
    if (lane == 0) mb[w] = bb;
  }
}

// ---------------- bf16 GEMM: C = A * W^T (+bias) * oscale ----------------
// BM=64, BN=128, BK=32, 256 threads (4 waves 2x2), 2-phase double-buffered LDS.
template <int OUTBF16, int HASBIAS>
__global__ __launch_bounds__(256) void gemm_bt(const bf16* __restrict__ A,
                                               const bf16* __restrict__ W,
                                               const float* __restrict__ bias,
                                               void* __restrict__ Cout,
                                               int M, int N, int K, float oscale) {
  __shared__ __align__(16) bf16 As[2][64 * 32];
  __shared__ __align__(16) bf16 Bs[2][128 * 32];

  const int t = threadIdx.x;
  const int w = t >> 6, lane = t & 63;
  const int l15 = lane & 15, lg = lane >> 4;
  const int wm = w >> 1, wn = w & 1;
  const int m0 = blockIdx.y * 64, n0 = blockIdx.x * 128;

  f32x4 acc[2][4] = {};

  const bf16* Ag  = A + (size_t)(m0 + w * 16 + (lane >> 2)) * K + (lane & 3) * 8;
  const bf16* Bg0 = W + (size_t)(n0 + w * 32 + (lane >> 2)) * K + (lane & 3) * 8;
  const bf16* Bg1 = W + (size_t)(n0 + w * 32 + 16 + (lane >> 2)) * K + (lane & 3) * 8;

  auto stage = [&](int nb, int k0) {
    async_copy16(Ag + k0, &As[nb][w * 512]);
    async_copy16(Bg0 + k0, &Bs[nb][w * 1024]);
    async_copy16(Bg1 + k0, &Bs[nb][w * 1024 + 512]);
  };

  stage(0, 0);
  int cur = 0;
  for (int k0 = 0; k0 < K; k0 += 32) {
    __syncthreads();                 // buf[cur] staged; prev reads done
    if (k0 + 32 < K) stage(cur ^ 1, k0 + 32);

    bf16x8 af[2], bfv[4];
#pragma unroll
    for (int mi = 0; mi < 2; ++mi)
      af[mi] = *(const bf16x8*)&As[cur][(wm * 32 + mi * 16 + l15) * 32 + lg * 8];
#pragma unroll
    for (int ni = 0; ni < 4; ++ni)
      bfv[ni] = *(const bf16x8*)&Bs[cur][(wn * 64 + ni * 16 + l15) * 32 + lg * 8];
#pragma unroll
    for (int mi = 0; mi < 2; ++mi)
#pragma unroll
      for (int ni = 0; ni < 4; ++ni)
        acc[mi][ni] = __builtin_amdgcn_mfma_f32_16x16x32_bf16(af[mi], bfv[ni],
                                                              acc[mi][ni], 0, 0, 0);
    cur ^= 1;
  }

#pragma unroll
  for (int mi = 0; mi < 2; ++mi)
#pragma unroll
    for (int ni = 0; ni < 4; ++ni)
#pragma unroll
      for (int r = 0; r < 4; ++r) {
        const int row = m0 + wm * 32 + mi * 16 + lg * 4 + r;
        const int col = n0 + wn * 64 + ni * 16 + l15;
        float v = acc[mi][ni][r] * oscale;
        if (HASBIAS) v += bias[col];
        if (OUTBF16) ((bf16*)Cout)[(size_t)row * N + col] = (bf16)v;
        else         ((float*)Cout)[(size_t)row * N + col] = v;
      }
}

// ---------------- V transpose + key-slot permute ----------------
// Vt[b][h][d][kt*64 + slot] = V[b][kt*64 + sigma(slot)][h*64+d]
// sigma within each 16-slot group: {0,1,2,3,8,9,10,11 | 4,5,6,7,12,13,14,15}
// so that PV's B-operand slots are exactly the keys each lane owns from S^T.
__global__ __launch_bounds__(256) void vtrans(const bf16* __restrict__ V,
                                              bf16* __restrict__ Vt) {
  __shared__ __align__(16) bf16 T[64][80];
  const int kt = blockIdx.x, h = blockIdx.y, b = blockIdx.z;
  const int t = threadIdx.x;
  {
    const int kl = t >> 2, db = (t & 3) * 16;
    const bf16* src = &V[((size_t)(b * C_NK + kt * 64 + kl)) * C_INNER + h * 64 + db];
    *(bf16x8*)&T[kl][db]     = *(const bf16x8*)&src[0];
    *(bf16x8*)&T[kl][db + 8] = *(const bf16x8*)&src[8];
  }
  __syncthreads();
  {
    const int d = t >> 2, kb = (t & 3) * 16;
    const int P0[8] = {0, 1, 2, 3, 8, 9, 10, 11};
    const int P1[8] = {4, 5, 6, 7, 12, 13, 14, 15};
    bf16x8 o0, o1;
#pragma unroll
    for (int j = 0; j < 8; ++j) { o0[j] = T[kb + P0[j]][d]; o1[j] = T[kb + P1[j]][d]; }
    bf16* dst = &Vt[((size_t)((b * C_H + h) * C_DH + d)) * C_NK + kt * 64 + kb];
    *(bf16x8*)&dst[0] = o0;
    *(bf16x8*)&dst[8] = o1;
  }
}

// ---------------- Flash cross-attention: swapped-QK^T 32x32 ----------------
// 128 threads = 2 waves, each wave owns 32 q-rows. KVBLK=64, K/V double-buffered.
// S^T = mfma(K, Q): lane(hi,l31) holds S^T[key=(reg&3)+8*(reg>>2)+4*hi+32*kb][q=l31].
// Softmax fully in-register; cross-half combines via __shfl_xor(.,32).
// P feeds PV's B-operand DIRECTLY (no LDS, no cross-lane): V columns are
// pre-permuted (vtrans) so slot j of block ks takes the lane's own key
// s[kb=ks>>1][ (ks&1)*8 + j ].  Q is pre-scaled by 0.125*log2(e).
__global__ __launch_bounds__(128) void attn_fwd(const bf16* __restrict__ Q,
                                                const bf16* __restrict__ K,
                                                const bf16* __restrict__ Vt,
                                                const unsigned long long* __restrict__ MB,
                                                bf16* __restrict__ AO) {
  __shared__ __align__(16) bf16 Ks[2][64 * 64];
  __shared__ __align__(16) bf16 Vs[2][64 * 64];

  const int qt = blockIdx.x, h = blockIdx.y, b = blockIdx.z;
  const int t = threadIdx.x, wq = t >> 6, lane = t & 63;
  const int l31 = lane & 31, hi = lane >> 5;
  const int q = qt * 64 + wq * 32 + l31;

  // Q fragments (B-operand): col=q, k-elems d = db*16 + hi*8 + j
  bf16x8 qf[4];
  {
    const bf16* qp = Q + ((size_t)(b * C_NQ + q)) * C_INNER + h * C_DH;
#pragma unroll
    for (int db = 0; db < 4; ++db)
      qf[db] = *(const bf16x8*)&qp[db * 16 + hi * 8];
  }

  float m_run = -3.0e38f, l_run = 0.f;
  f32x16 acc_o[2] = {};   // O^T: col=q, row d = d2*32 + (reg&3)+8*(reg>>2)+4*hi

  auto stage = [&](int nb, int kt) {
#pragma unroll
    for (int c = 0; c < 4; ++c) {
      const int chunk = wq * 256 + c * 64 + lane;   // 0..511 (16B chunks)
      const int row = chunk >> 3, pcb = chunk & 7;
      const int srcb = (pcb ^ (row & 7)) * 8;       // pre-swizzled global source
      const bf16* kg = K + ((size_t)(b * C_NK + kt * 64 + row)) * C_INNER + h * C_DH + srcb;
      async_copy16(kg, &Ks[nb][(wq * 256 + c * 64) * 8]);
      const bf16* vg = Vt + ((size_t)((b * C_H + h) * C_DH + row)) * C_NK + kt * 64 + srcb;
      async_copy16(vg, &Vs[nb][(wq * 256 + c * 64) * 8]);
    }
  };

  stage(0, 0);
  int cur = 0;
  const int NT = C_NK / 64;

  for (int kt = 0; kt < NT; ++kt) {
    const unsigned long long wd =
        MB[((size_t)(b * C_NQ + q)) * NT + kt] >> (hi * 4);
    const unsigned mlo = (unsigned)wd, mhi = (unsigned)(wd >> 32);

    __syncthreads();                  // buf[cur] staged; prev-tile reads done
    if (kt + 1 < NT) stage(cur ^ 1, kt + 1);

    // ---- QK^T: S^T[key][q], acc per 32-key block ----
    f32x16 s[2] = {};
    __builtin_amdgcn_s_setprio(1);
#pragma unroll
    for (int kb = 0; kb < 2; ++kb)
#pragma unroll
      for (int db = 0; db < 4; ++db) {
        const int row = kb * 32 + l31;
        const int cb = (db * 2 + hi) ^ (row & 7);
        bf16x8 kf = *(const bf16x8*)&Ks[cur][row * 64 + cb * 8];
        s[kb] = __builtin_amdgcn_mfma_f32_32x32x16_bf16(kf, qf[db], s[kb], 0, 0, 0);
      }
    __builtin_amdgcn_s_setprio(0);

    // ---- mask + row max (bit pos = (reg&3)+8*(reg>>2) in hi-shifted word) ----
    float pm = -1.0e30f;
#pragma unroll
    for (int kb = 0; kb < 2; ++kb) {
      const unsigned mw = kb ? mhi : mlo;
#pragma unroll
      for (int reg = 0; reg < 16; ++reg) {
        const int pos = (reg & 3) + 8 * (reg >> 2);
        const float v = ((mw >> pos) & 1u) ? s[kb][reg] : -1.0e30f;
        s[kb][reg] = v;
        pm = fmaxf(pm, v);
      }
    }
    pm = fmaxf(pm, __shfl_xor(pm, 32));   // combine across hi halves

    // ---- defer-max online update (T13): rescale only when max grows >8 ----
    if (!__all(pm <= m_run + 8.0f)) {
      const float mn = fmaxf(m_run, pm);
      const float f = EXP2(m_run - mn);
      m_run = mn;
      l_run *= f;
#pragma unroll
      for (int d2 = 0; d2 < 2; ++d2)
#pragma unroll
        for (int reg = 0; reg < 16; ++reg)
          acc_o[d2][reg] *= f;
    }

    // ---- exp2 + pack P into PV B-frags (lane-local, slot-matched to V perm) ----
    bf16x8 pfr[4];
    float ps = 0.f;
#pragma unroll
    for (int kb = 0; kb < 2; ++kb)
#pragma unroll
      for (int kss = 0; kss < 2; ++kss) {
        bf16x8 pf;
#pragma unroll
        for (int j = 0; j < 8; ++j) {
          const float p = EXP2(s[kb][kss * 8 + j] - m_run);
          ps += p;
          pf[j] = (bf16)p;
        }
        pfr[kb * 2 + kss] = pf;
      }
    l_run += ps;   // own-half (32 keys) partial; combined across hi at the end

    // ---- PV: O^T += V^T * P ----
    __builtin_amdgcn_s_setprio(1);
#pragma unroll
    for (int ks = 0; ks < 4; ++ks) {
#pragma unroll
      for (int d2 = 0; d2 < 2; ++d2) {
        const int row = d2 * 32 + l31;
        const int cb = (ks * 2 + hi) ^ (row & 7);
        bf16x8 vf = *(const bf16x8*)&Vs[cur][row * 64 + cb * 8];
        acc_o[d2] = __builtin_amdgcn_mfma_f32_32x32x16_bf16(vf, pfr[ks], acc_o[d2], 0, 0, 0);
      }
    }
    __builtin_amdgcn_s_setprio(0);
    cur ^= 1;
  }

  // ---- epilogue: combine l across hi halves, normalize, store ----
  {
    const float ltot = l_run + __shfl_xor(l_run, 32);
    const float inv = 1.0f / ltot;
    bf16* op = AO + ((size_t)(b * C_NQ + q)) * C_INNER + h * C_DH;
#pragma unroll
    for (int d2 = 0; d2 < 2; ++d2)
#pragma unroll
      for (int bb = 0; bb < 4; ++bb) {
        bf16x4 o;
#pragma unroll
        for (int rr = 0; rr < 4; ++rr)
          o[rr] = (bf16)(acc_o[d2][bb * 4 + rr] * inv);
        *(bf16x4*)&op[d2 * 32 + bb * 8 + hi * 4] = o;
      }
  }
}

// ---------------- launch ----------------
extern "C" void kernel_launch(void* const* d_in, const int* in_sizes, int n_in,
                              void* d_out, int out_size, void* d_ws, size_t ws_size,
                              hipStream_t stream) {
  const float* x   = (const float*)d_in[0];
  const float* ctx = (const float*)d_in[1];
  const int*   msk = (const int*)d_in[2];
  const float* Wq  = (const float*)d_in[3];
  const float* Wk  = (const float*)d_in[4];
  const float* Wv  = (const float*)d_in[5];
  const float* Wo  = (const float*)d_in[6];
  const float* bo  = (const float*)d_in[7];
  float* out = (float*)d_out;

  // workspace layout (bf16 elems). Vtb ALIASES xb (x dead after Q proj).
  bf16* ws  = (bf16*)d_ws;
  bf16* xb  = ws;                   // 4,194,304
  bf16* cb  = xb  + 4194304;        // 3,145,728
  bf16* wqb = cb  + 3145728;        // 1,048,576
  bf16* wkb = wqb + 1048576;        //   786,432
  bf16* wvb = wkb + 786432;         //   786,432
  bf16* wob = wvb + 786432;         // 1,048,576
  bf16* Qb  = wob + 1048576;        // 4,194,304
  bf16* Kb  = Qb  + 4194304;
  bf16* Vb  = Kb  + 4194304;
  bf16* AOb = Vb  + 4194304;
  unsigned long long* mb = (unsigned long long*)(AOb + 4194304);
  bf16* Vtb = xb;                   // alias

  dim3 blk(256);
  auto cvt = [&](const float* s, bf16* d, int n) {
    int blocks = (n / 4 + 255) / 256;
    if (blocks > 2048) blocks = 2048;
    cvtk<<<blocks, blk, 0, stream>>>(s, d, n);
  };
  cvt(x,   xb,  C_B * C_NQ * C_QD);
  cvt(ctx, cb,  C_B * C_NK * C_CD);
  cvt(Wq,  wqb, C_INNER * C_QD);
  cvt(Wk,  wkb, C_INNER * C_CD);
  cvt(Wv,  wvb, C_INNER * C_CD);
  cvt(Wo,  wob, C_QD * C_INNER);

  pack_mask<<<512, blk, 0, stream>>>(msk, mb, C_B * C_NQ * (C_NK / 64));

  const int MQ = C_B * C_NQ;  // 4096
  const float qscale = 0.125f * 1.44269504f;  // DH^-0.5 * log2(e), folded into Q
  gemm_bt<1, 0><<<dim3(C_INNER / 128, MQ / 64), blk, 0, stream>>>(xb, wqb, nullptr, Qb, MQ, C_INNER, C_QD, qscale);
  gemm_bt<1, 0><<<dim3(C_INNER / 128, MQ / 64), blk, 0, stream>>>(cb, wkb, nullptr, Kb, MQ, C_INNER, C_CD, 1.0f);
  gemm_bt<1, 0><<<dim3(C_INNER / 128, MQ / 64), blk, 0, stream>>>(cb, wvb, nullptr, Vb, MQ, C_INNER, C_CD, 1.0f);

  vtrans<<<dim3(C_NK / 64, C_H, C_B), blk, 0, stream>>>(Vb, Vtb);

  attn_fwd<<<dim3(C_NQ / 64, C_H, C_B), dim3(128), 0, stream>>>(Qb, Kb, Vtb, mb, AOb);

  gemm_bt<0, 1><<<dim3(C_QD / 128, MQ / 64), blk, 0, stream>>>(AOb, wob, bo, out, MQ, C_QD, C_INNER, 1.0f);
}

// Round 7
// 178.653 us; speedup vs baseline: 5.7356x; 1.0999x over previous
//
#include <hip/hip_runtime.h>
#include <float.h>
#include <stdint.h>

#define C_B     2
#define C_NQ    2048
#define C_NK    2048
#define C_QD    1024
#define C_CD    768
#define C_H     16
#define C_DH    64
#define C_INNER 1024

typedef __bf16 bf16;
typedef __attribute__((ext_vector_type(8))) __bf16 bf16x8;
typedef __attribute__((ext_vector_type(4))) __bf16 bf16x4;
typedef __attribute__((ext_vector_type(4))) float f32x4;
typedef __attribute__((ext_vector_type(16))) float f32x16;

#if __has_builtin(__builtin_amdgcn_exp2f)
#define EXP2(x) __builtin_amdgcn_exp2f(x)
#else
#define EXP2(x) __expf((x) * 0.69314718056f)
#endif

// ---- async global->LDS, 16B per lane. LDS dest is wave-uniform base + lane*16. ----
__device__ __forceinline__ void async_copy16(const bf16* g, bf16* l) {
  __builtin_amdgcn_global_load_lds(
      (const __attribute__((address_space(1))) void*)g,
      (__attribute__((address_space(3))) void*)l,
      16, 0, 0);
}

// ---------------- fused f32 -> bf16 convert (all 6 tensors, one launch) ----------
__global__ __launch_bounds__(256) void cvt_all(const float* __restrict__ s0, const float* __restrict__ s1,
                                               const float* __restrict__ s2, const float* __restrict__ s3,
                                               const float* __restrict__ s4, const float* __restrict__ s5,
                                               bf16* __restrict__ d0, bf16* __restrict__ d1,
                                               bf16* __restrict__ d2, bf16* __restrict__ d3,
                                               bf16* __restrict__ d4, bf16* __restrict__ d5) {
  // sizes in float4 units; prefix boundaries
  const int stride = gridDim.x * blockDim.x;
  for (int idx = blockIdx.x * blockDim.x + threadIdx.x; idx < 2752512; idx += stride) {
    const float* src; bf16* dst; int loc;
    if      (idx < 1048576) { src = s0; dst = d0; loc = idx; }
    else if (idx < 1835008) { src = s1; dst = d1; loc = idx - 1048576; }
    else if (idx < 2097152) { src = s2; dst = d2; loc = idx - 1835008; }
    else if (idx < 2293760) { src = s3; dst = d3; loc = idx - 2097152; }
    else if (idx < 2490368) { src = s4; dst = d4; loc = idx - 2293760; }
    else                    { src = s5; dst = d5; loc = idx - 2490368; }
    float4 f = *(const float4*)&src[loc * 4];
    bf16x4 o = { (bf16)f.x, (bf16)f.y, (bf16)f.z, (bf16)f.w };
    *(bf16x4*)&dst[loc * 4] = o;
  }
}

// ---------------- mask int32 -> bitmask (u64 per 64 keys) ----------------
__global__ __launch_bounds__(256) void pack_mask(const int* __restrict__ mask,
                                                 unsigned long long* __restrict__ mb,
                                                 int nwords) {
  const int wid  = (blockIdx.x * blockDim.x + threadIdx.x) >> 6;
  const int lane = threadIdx.x & 63;
  const int nw   = (gridDim.x * blockDim.x) >> 6;
  for (int w = wid; w < nwords; w += nw) {
    int v = mask[(size_t)w * 64 + lane];
    unsigned long long bb = __ballot(v != 0);
    if (lane == 0) mb[w] = bb;
  }
}

// ---------------- bf16 GEMM: C = A * W^T (+bias) * oscale, split-output ----------
// BM=64, BN=128, BK=32, 256 threads (4 waves 2x2), 2-phase double-buffered LDS.
// Columns >= ncut route to Cout2 (for fused K|V projection).
template <int OUTBF16, int HASBIAS>
__global__ __launch_bounds__(256) void gemm_bt(const bf16* __restrict__ A,
                                               const bf16* __restrict__ W,
                                               const float* __restrict__ bias,
                                               void* __restrict__ Cout,
                                               int M, int N, int K, float oscale,
                                               int ncut, bf16* __restrict__ Cout2) {
  __shared__ __align__(16) bf16 As[2][64 * 32];
  __shared__ __align__(16) bf16 Bs[2][128 * 32];

  const int t = threadIdx.x;
  const int w = t >> 6, lane = t & 63;
  const int l15 = lane & 15, lg = lane >> 4;
  const int wm = w >> 1, wn = w & 1;
  const int m0 = blockIdx.y * 64, n0 = blockIdx.x * 128;

  f32x4 acc[2][4] = {};

  const bf16* Ag  = A + (size_t)(m0 + w * 16 + (lane >> 2)) * K + (lane & 3) * 8;
  const bf16* Bg0 = W + (size_t)(n0 + w * 32 + (lane >> 2)) * K + (lane & 3) * 8;
  const bf16* Bg1 = W + (size_t)(n0 + w * 32 + 16 + (lane >> 2)) * K + (lane & 3) * 8;

  auto stage = [&](int nb, int k0) {
    async_copy16(Ag + k0, &As[nb][w * 512]);
    async_copy16(Bg0 + k0, &Bs[nb][w * 1024]);
    async_copy16(Bg1 + k0, &Bs[nb][w * 1024 + 512]);
  };

  stage(0, 0);
  int cur = 0;
  for (int k0 = 0; k0 < K; k0 += 32) {
    __syncthreads();                 // buf[cur] staged; prev reads done
    if (k0 + 32 < K) stage(cur ^ 1, k0 + 32);

    bf16x8 af[2], bfv[4];
#pragma unroll
    for (int mi = 0; mi < 2; ++mi)
      af[mi] = *(const bf16x8*)&As[cur][(wm * 32 + mi * 16 + l15) * 32 + lg * 8];
#pragma unroll
    for (int ni = 0; ni < 4; ++ni)
      bfv[ni] = *(const bf16x8*)&Bs[cur][(wn * 64 + ni * 16 + l15) * 32 + lg * 8];
#pragma unroll
    for (int mi = 0; mi < 2; ++mi)
#pragma unroll
      for (int ni = 0; ni < 4; ++ni)
        acc[mi][ni] = __builtin_amdgcn_mfma_f32_16x16x32_bf16(af[mi], bfv[ni],
                                                              acc[mi][ni], 0, 0, 0);
    cur ^= 1;
  }

#pragma unroll
  for (int mi = 0; mi < 2; ++mi)
#pragma unroll
    for (int ni = 0; ni < 4; ++ni)
#pragma unroll
      for (int r = 0; r < 4; ++r) {
        const int row = m0 + wm * 32 + mi * 16 + lg * 4 + r;
        const int col = n0 + wn * 64 + ni * 16 + l15;
        float v = acc[mi][ni][r] * oscale;
        if (HASBIAS) v += bias[col];
        if (OUTBF16) {
          bf16* dst; int cc, str;
          if (col < ncut) { dst = (bf16*)Cout; cc = col; str = ncut; }
          else            { dst = Cout2; cc = col - ncut; str = N - ncut; }
          dst[(size_t)row * str + cc] = (bf16)v;
        } else {
          ((float*)Cout)[(size_t)row * N + col] = v;
        }
      }
}

// ---------------- V transpose + key-slot permute ----------------
// Vt[b][h][d][kt*64 + slot] = V[b][kt*64 + sigma(slot)][h*64+d]
// sigma per 16-slot group: {0,1,2,3,8,9,10,11 | 4,5,6,7,12,13,14,15}
__global__ __launch_bounds__(256) void vtrans(const bf16* __restrict__ V,
                                              bf16* __restrict__ Vt) {
  __shared__ __align__(16) bf16 T[64][80];
  const int kt = blockIdx.x, h = blockIdx.y, b = blockIdx.z;
  const int t = threadIdx.x;
  {
    const int kl = t >> 2, db = (t & 3) * 16;
    const bf16* src = &V[((size_t)(b * C_NK + kt * 64 + kl)) * C_INNER + h * 64 + db];
    *(bf16x8*)&T[kl][db]     = *(const bf16x8*)&src[0];
    *(bf16x8*)&T[kl][db + 8] = *(const bf16x8*)&src[8];
  }
  __syncthreads();
  {
    const int d = t >> 2, kb = (t & 3) * 16;
    const int P0[8] = {0, 1, 2, 3, 8, 9, 10, 11};
    const int P1[8] = {4, 5, 6, 7, 12, 13, 14, 15};
    bf16x8 o0, o1;
#pragma unroll
    for (int j = 0; j < 8; ++j) { o0[j] = T[kb + P0[j]][d]; o1[j] = T[kb + P1[j]][d]; }
    bf16* dst = &Vt[((size_t)((b * C_H + h) * C_DH + d)) * C_NK + kt * 64 + kb];
    *(bf16x8*)&dst[0] = o0;
    *(bf16x8*)&dst[8] = o1;
  }
}

// ---------------- Flash cross-attention: swapped-QK^T 32x32, split-K2 ----------
// Grid (NQ/64, H, B*2): z -> {half, b}. 128 threads = 2 waves, 32 q-rows each.
// KVBLK=32 (LDS 16KB -> 8 blocks/CU), K/V double-buffered, partial (O,m,l) out.
#define KVB 32
__global__ __launch_bounds__(128, 4) void attn_fwd(const bf16* __restrict__ Q,
                                                   const bf16* __restrict__ K,
                                                   const bf16* __restrict__ Vt,
                                                   const unsigned long long* __restrict__ MB,
                                                   bf16* __restrict__ O0,
                                                   bf16* __restrict__ O1,
                                                   float2* __restrict__ LM) {
  __shared__ __align__(16) bf16 Ks[2][KVB * 64];   // 32 key-rows x 64 d (128B rows)
  __shared__ __align__(16) bf16 Vs[2][64 * KVB];   // 64 d-rows x 32 key (64B rows)

  const int qt = blockIdx.x, h = blockIdx.y;
  const int half = blockIdx.z >> 1, b = blockIdx.z & 1;
  const int t = threadIdx.x, wq = t >> 6, lane = t & 63;
  const int l31 = lane & 31, hi = lane >> 5;
  const int q = qt * 64 + wq * 32 + l31;

  // Q fragments (B-operand): col=q, k-elems d = db*16 + hi*8 + j
  bf16x8 qf[4];
  {
    const bf16* qp = Q + ((size_t)(b * C_NQ + q)) * C_INNER + h * C_DH;
#pragma unroll
    for (int db = 0; db < 4; ++db)
      qf[db] = *(const bf16x8*)&qp[db * 16 + hi * 8];
  }

  float m_run = -3.0e38f, l_run = 0.f;
  f32x16 acc_o[2] = {};   // O^T: col=q, row d = d2*32 + (reg&3)+8*(reg>>2)+4*hi

  auto stage = [&](int nb, int ktA) {
#pragma unroll
    for (int c = 0; c < 2; ++c) {
      const int chunk = wq * 128 + c * 64 + lane;   // 0..255 (16B chunks)
      // K tile: 32 rows x 8 chunks
      const int krow = chunk >> 3, kpcb = chunk & 7;
      const int ksrc = (kpcb ^ (krow & 7)) * 8;
      const bf16* kg = K + ((size_t)(b * C_NK + ktA * KVB + krow)) * C_INNER + h * C_DH + ksrc;
      async_copy16(kg, &Ks[nb][chunk * 8]);
      // V tile: 64 rows x 4 chunks
      const int vrow = chunk >> 2, vpcb = chunk & 3;
      const int vsrc = (vpcb ^ (vrow & 3)) * 8;
      const bf16* vg = Vt + ((size_t)((b * C_H + h) * C_DH + vrow)) * C_NK + ktA * KVB + vsrc;
      async_copy16(vg, &Vs[nb][chunk * 8]);
    }
  };

  const int kt0 = half * 32;          // 32 tiles of 32 keys per half
  stage(0, kt0);
  int cur = 0;

  for (int i = 0; i < 32; ++i) {
    const int ktA = kt0 + i;
    // mask bits for this lane's q-row, this 32-key tile (issued before barrier)
    const unsigned mw = (unsigned)(
        MB[((size_t)(b * C_NQ + q)) * (C_NK / 64) + (ktA >> 1)] >>
        ((ktA & 1) * 32 + hi * 4));

    __syncthreads();                  // buf[cur] staged; prev-tile reads done
    if (i + 1 < 32) stage(cur ^ 1, ktA + 1);

    // ---- QK^T: S^T[key][q] ----
    f32x16 s = {};
    __builtin_amdgcn_s_setprio(1);
#pragma unroll
    for (int db = 0; db < 4; ++db) {
      const int row = l31;
      const int cb = (db * 2 + hi) ^ (row & 7);
      bf16x8 kf = *(const bf16x8*)&Ks[cur][row * 64 + cb * 8];
      s = __builtin_amdgcn_mfma_f32_32x32x16_bf16(kf, qf[db], s, 0, 0, 0);
    }
    __builtin_amdgcn_s_setprio(0);

    // ---- row max over RAW s (safe upper bound; mask applied at exp) ----
    float pm = -1.0e30f;
#pragma unroll
    for (int reg = 0; reg < 16; ++reg) pm = fmaxf(pm, s[reg]);
    pm = fmaxf(pm, __shfl_xor(pm, 32));

    // ---- defer-max online update: rescale only when max grows >8 ----
    if (!__all(pm <= m_run + 8.0f)) {
      const float mn = fmaxf(m_run, pm);
      const float f = EXP2(m_run - mn);
      m_run = mn;
      l_run *= f;
#pragma unroll
      for (int d2 = 0; d2 < 2; ++d2)
#pragma unroll
        for (int reg = 0; reg < 16; ++reg)
          acc_o[d2][reg] *= f;
    }

    // ---- exp2 + mask-zero + pack P (lane-local; V pre-permuted to match) ----
    bf16x8 pfr[2];
    float ps = 0.f;
#pragma unroll
    for (int kss = 0; kss < 2; ++kss) {
      bf16x8 pf;
#pragma unroll
      for (int j = 0; j < 8; ++j) {
        const int reg = kss * 8 + j;
        const int pos = (reg & 3) + 8 * (reg >> 2);
        float p = EXP2(s[reg] - m_run);
        p = ((mw >> pos) & 1u) ? p : 0.f;
        ps += p;
        pf[j] = (bf16)p;
      }
      pfr[kss] = pf;
    }
    l_run += ps;   // own-half (32 keys) partial; combined across hi at the end

    // ---- PV: O^T += V^T * P ----
    __builtin_amdgcn_s_setprio(1);
#pragma unroll
    for (int ks = 0; ks < 2; ++ks) {
#pragma unroll
      for (int d2 = 0; d2 < 2; ++d2) {
        const int row = d2 * 32 + l31;
        const int cb = (ks * 2 + hi) ^ (row & 3);
        bf16x8 vf = *(const bf16x8*)&Vs[cur][row * KVB + cb * 8];
        acc_o[d2] = __builtin_amdgcn_mfma_f32_32x32x16_bf16(vf, pfr[ks], acc_o[d2], 0, 0, 0);
      }
    }
    __builtin_amdgcn_s_setprio(0);
    cur ^= 1;
  }

  // ---- epilogue: store UNNORMALIZED partial O (bf16) + (m, l) ----
  {
    const float l_tot = l_run + __shfl_xor(l_run, 32);
    const size_t row = (size_t)(b * C_H + h) * C_NQ + q;
    bf16* op = (half ? O1 : O0) + row * 64;
#pragma unroll
    for (int d2 = 0; d2 < 2; ++d2)
#pragma unroll
      for (int bb = 0; bb < 4; ++bb) {
        bf16x4 o;
#pragma unroll
        for (int rr = 0; rr < 4; ++rr)
          o[rr] = (bf16)(acc_o[d2][bb * 4 + rr]);
        *(bf16x4*)&op[d2 * 32 + bb * 8 + hi * 4] = o;
      }
    if (hi == 0) LM[(size_t)half * 65536 + row] = make_float2(m_run, l_tot);
  }
}

// ---------------- merge the two K-halves ----------------
__global__ __launch_bounds__(256) void merge_halves(const bf16* __restrict__ O0,
                                                    const bf16* __restrict__ O1,
                                                    const float2* __restrict__ LM,
                                                    bf16* __restrict__ AO) {
  const int t = threadIdx.x;
  const int r = blockIdx.x * 32 + (t >> 3);   // row 0..65535 = (b*H+h)*NQ + q
  const int dc = (t & 7) * 8;
  const float2 lm0 = LM[r], lm1 = LM[65536 + r];
  const float ms = fmaxf(lm0.x, lm1.x);
  const float w0 = EXP2(lm0.x - ms), w1 = EXP2(lm1.x - ms);
  const float denom = lm0.y * w0 + lm1.y * w1;
  const float s0 = w0 / denom, s1 = w1 / denom;
  bf16x8 a = *(const bf16x8*)&O0[(size_t)r * 64 + dc];
  bf16x8 c = *(const bf16x8*)&O1[(size_t)r * 64 + dc];
  bf16x8 o;
#pragma unroll
  for (int j = 0; j < 8; ++j)
    o[j] = (bf16)((float)a[j] * s0 + (float)c[j] * s1);
  const int q = r & 2047, bh = r >> 11, hh = bh & 15, bb = bh >> 4;
  *(bf16x8*)&AO[((size_t)(bb * C_NQ + q)) * C_INNER + hh * 64 + dc] = o;
}

// ---------------- launch ----------------
extern "C" void kernel_launch(void* const* d_in, const int* in_sizes, int n_in,
                              void* d_out, int out_size, void* d_ws, size_t ws_size,
                              hipStream_t stream) {
  const float* x   = (const float*)d_in[0];
  const float* ctx = (const float*)d_in[1];
  const int*   msk = (const int*)d_in[2];
  const float* Wq  = (const float*)d_in[3];
  const float* Wk  = (const float*)d_in[4];
  const float* Wv  = (const float*)d_in[5];
  const float* Wo  = (const float*)d_in[6];
  const float* bo  = (const float*)d_in[7];
  float* out = (float*)d_out;

  // workspace layout (bf16 elems). Aliases: Vtb=xb (x dead after Q-GEMM);
  // O0 = cb..wqb region (dead after GEMMs); O1 = Vb (dead after vtrans).
  bf16* ws  = (bf16*)d_ws;
  bf16* xb  = ws;                   // 4,194,304
  bf16* cb  = xb  + 4194304;        // 3,145,728
  bf16* wqb = cb  + 3145728;        // 1,048,576
  bf16* wkb = wqb + 1048576;        //   786,432  (Wk stacked with Wv -> [2048][768])
  bf16* wvb = wkb + 786432;         //   786,432
  bf16* wob = wvb + 786432;         // 1,048,576
  bf16* Qb  = wob + 1048576;        // 4,194,304
  bf16* Kb  = Qb  + 4194304;
  bf16* Vb  = Kb  + 4194304;
  bf16* AOb = Vb  + 4194304;
  unsigned long long* mb = (unsigned long long*)(AOb + 4194304);   // 131072 u64
  float2* lm = (float2*)(mb + 131072);                             // 131072 float2
  bf16* Vtb = xb;                   // alias
  bf16* O0  = cb;                   // alias (cb+wqb = 4,194,304 elems exactly)
  bf16* O1  = Vb;                   // alias

  dim3 blk(256);
  cvt_all<<<2048, blk, 0, stream>>>(x, ctx, Wq, Wk, Wv, Wo, xb, cb, wqb, wkb, wvb, wob);

  pack_mask<<<512, blk, 0, stream>>>(msk, mb, C_B * C_NQ * (C_NK / 64));

  const int MQ = C_B * C_NQ;  // 4096
  const float qscale = 0.125f * 1.44269504f;  // DH^-0.5 * log2(e), folded into Q
  // Q projection
  gemm_bt<1, 0><<<dim3(C_INNER / 128, MQ / 64), blk, 0, stream>>>(
      xb, wqb, nullptr, Qb, MQ, C_INNER, C_QD, qscale, C_INNER, nullptr);
  // fused K|V projection: W = [Wk; Wv] (contiguous), cols >=1024 -> Vb
  gemm_bt<1, 0><<<dim3(2 * C_INNER / 128, MQ / 64), blk, 0, stream>>>(
      cb, wkb, nullptr, Kb, MQ, 2 * C_INNER, C_CD, 1.0f, C_INNER, Vb);

  vtrans<<<dim3(C_NK / 64, C_H, C_B), blk, 0, stream>>>(Vb, Vtb);

  attn_fwd<<<dim3(C_NQ / 64, C_H, 2 * C_B), dim3(128), 0, stream>>>(
      Qb, Kb, Vtb, mb, O0, O1, lm);

  merge_halves<<<2048, blk, 0, stream>>>(O0, O1, lm, AOb);

  gemm_bt<0, 1><<<dim3(C_QD / 128, MQ / 64), blk, 0, stream>>>(
      AOb, wob, bo, out, MQ, C_QD, C_INNER, 1.0f, C_QD, nullptr);
}

// Round 8
// 173.424 us; speedup vs baseline: 5.9086x; 1.0302x over previous
//
#include <hip/hip_runtime.h>
#include <float.h>
#include <stdint.h>

#define C_B     2
#define C_NQ    2048
#define C_NK    2048
#define C_QD    1024
#define C_CD    768
#define C_H     16
#define C_DH    64
#define C_INNER 1024

typedef __bf16 bf16;
typedef __attribute__((ext_vector_type(8))) __bf16 bf16x8;
typedef __attribute__((ext_vector_type(4))) __bf16 bf16x4;
typedef __attribute__((ext_vector_type(4))) float f32x4;
typedef __attribute__((ext_vector_type(16))) float f32x16;

#if __has_builtin(__builtin_amdgcn_exp2f)
#define EXP2(x) __builtin_amdgcn_exp2f(x)
#else
#define EXP2(x) __expf((x) * 0.69314718056f)
#endif

// ---- async global->LDS, 16B per lane. LDS dest is wave-uniform base + lane*16. ----
__device__ __forceinline__ void async_copy16(const bf16* g, bf16* l) {
  __builtin_amdgcn_global_load_lds(
      (const __attribute__((address_space(1))) void*)g,
      (__attribute__((address_space(3))) void*)l,
      16, 0, 0);
}

// ---------------- fused f32 -> bf16 convert (all 6 tensors, one launch) ----------
__global__ __launch_bounds__(256) void cvt_all(const float* __restrict__ s0, const float* __restrict__ s1,
                                               const float* __restrict__ s2, const float* __restrict__ s3,
                                               const float* __restrict__ s4, const float* __restrict__ s5,
                                               bf16* __restrict__ d0, bf16* __restrict__ d1,
                                               bf16* __restrict__ d2, bf16* __restrict__ d3,
                                               bf16* __restrict__ d4, bf16* __restrict__ d5) {
  const int stride = gridDim.x * blockDim.x;
  for (int idx = blockIdx.x * blockDim.x + threadIdx.x; idx < 2752512; idx += stride) {
    const float* src; bf16* dst; int loc;
    if      (idx < 1048576) { src = s0; dst = d0; loc = idx; }
    else if (idx < 1835008) { src = s1; dst = d1; loc = idx - 1048576; }
    else if (idx < 2097152) { src = s2; dst = d2; loc = idx - 1835008; }
    else if (idx < 2293760) { src = s3; dst = d3; loc = idx - 2097152; }
    else if (idx < 2490368) { src = s4; dst = d4; loc = idx - 2293760; }
    else                    { src = s5; dst = d5; loc = idx - 2490368; }
    float4 f = *(const float4*)&src[loc * 4];
    bf16x4 o = { (bf16)f.x, (bf16)f.y, (bf16)f.z, (bf16)f.w };
    *(bf16x4*)&dst[loc * 4] = o;
  }
}

// ---------------- mask int32 -> bitmask (u64 per 64 keys) ----------------
__global__ __launch_bounds__(256) void pack_mask(const int* __restrict__ mask,
                                                 unsigned long long* __restrict__ mb,
                                                 int nwords) {
  const int wid  = (blockIdx.x * blockDim.x + threadIdx.x) >> 6;
  const int lane = threadIdx.x & 63;
  const int nw   = (gridDim.x * blockDim.x) >> 6;
  for (int w = wid; w < nwords; w += nw) {
    int v = mask[(size_t)w * 64 + lane];
    unsigned long long bb = __ballot(v != 0);
    if (lane == 0) mb[w] = bb;
  }
}

// ---------------- bf16 GEMM: C = A * W^T (+bias) * oscale, split-output ----------
// 128x128 tile, BK=32, 256 threads (4 waves 2x2, each 64x64), dbuf LDS,
// XOR-swizzled staging (pre-swizzled global source, swizzled ds_read).
template <int OUTBF16, int HASBIAS>
__global__ __launch_bounds__(256) void gemm_bt(const bf16* __restrict__ A,
                                               const bf16* __restrict__ W,
                                               const float* __restrict__ bias,
                                               void* __restrict__ Cout,
                                               int M, int N, int K, float oscale,
                                               int ncut, bf16* __restrict__ Cout2) {
  __shared__ __align__(16) bf16 As[2][128 * 32];
  __shared__ __align__(16) bf16 Bs[2][128 * 32];

  const int t = threadIdx.x;
  const int w = t >> 6, lane = t & 63;
  const int l15 = lane & 15, lg = lane >> 4;
  const int wm = w >> 1, wn = w & 1;
  const int m0 = blockIdx.y * 128, n0 = blockIdx.x * 128;

  f32x4 acc[4][4] = {};

  // staging: 512 chunks of 16B per matrix; chunk = row*4 + kblk, LDS linear.
  // global source pre-swizzled: kblk_src = kblk ^ (row&3).
  auto stage = [&](int nb, int k0) {
#pragma unroll
    for (int i = 0; i < 2; ++i) {
      const int chunk = w * 128 + i * 64 + lane;
      const int row = chunk >> 2;
      const int srcb = ((chunk & 3) ^ (row & 3)) * 8;
      async_copy16(A + (size_t)(m0 + row) * K + k0 + srcb, &As[nb][chunk * 8]);
      async_copy16(W + (size_t)(n0 + row) * K + k0 + srcb, &Bs[nb][chunk * 8]);
    }
  };

  stage(0, 0);
  int cur = 0;
  for (int k0 = 0; k0 < K; k0 += 32) {
    __syncthreads();                 // buf[cur] staged; prev reads done
    if (k0 + 32 < K) stage(cur ^ 1, k0 + 32);

    bf16x8 af[4], bfv[4];
#pragma unroll
    for (int mi = 0; mi < 4; ++mi) {
      const int row = wm * 64 + mi * 16 + l15;
      af[mi] = *(const bf16x8*)&As[cur][row * 32 + ((lg ^ (row & 3)) * 8)];
    }
#pragma unroll
    for (int ni = 0; ni < 4; ++ni) {
      const int row = wn * 64 + ni * 16 + l15;
      bfv[ni] = *(const bf16x8*)&Bs[cur][row * 32 + ((lg ^ (row & 3)) * 8)];
    }
#pragma unroll
    for (int mi = 0; mi < 4; ++mi)
#pragma unroll
      for (int ni = 0; ni < 4; ++ni)
        acc[mi][ni] = __builtin_amdgcn_mfma_f32_16x16x32_bf16(af[mi], bfv[ni],
                                                              acc[mi][ni], 0, 0, 0);
    cur ^= 1;
  }

#pragma unroll
  for (int mi = 0; mi < 4; ++mi)
#pragma unroll
    for (int ni = 0; ni < 4; ++ni)
#pragma unroll
      for (int r = 0; r < 4; ++r) {
        const int row = m0 + wm * 64 + mi * 16 + lg * 4 + r;
        const int col = n0 + wn * 64 + ni * 16 + l15;
        float v = acc[mi][ni][r] * oscale;
        if (HASBIAS) v += bias[col];
        if (OUTBF16) {
          bf16* dst; int cc, str;
          if (col < ncut) { dst = (bf16*)Cout; cc = col; str = ncut; }
          else            { dst = Cout2; cc = col - ncut; str = N - ncut; }
          dst[(size_t)row * str + cc] = (bf16)v;
        } else {
          ((float*)Cout)[(size_t)row * N + col] = v;
        }
      }
}

// ---------------- V transpose + key-slot permute ----------------
// Vt[b][h][d][kt*64 + slot] = V[b][kt*64 + sigma(slot)][h*64+d]
// sigma per 16-slot group: {0,1,2,3,8,9,10,11 | 4,5,6,7,12,13,14,15}
__global__ __launch_bounds__(256) void vtrans(const bf16* __restrict__ V,
                                              bf16* __restrict__ Vt) {
  __shared__ __align__(16) bf16 T[64][80];
  const int kt = blockIdx.x, h = blockIdx.y, b = blockIdx.z;
  const int t = threadIdx.x;
  {
    const int kl = t >> 2, db = (t & 3) * 16;
    const bf16* src = &V[((size_t)(b * C_NK + kt * 64 + kl)) * C_INNER + h * 64 + db];
    *(bf16x8*)&T[kl][db]     = *(const bf16x8*)&src[0];
    *(bf16x8*)&T[kl][db + 8] = *(const bf16x8*)&src[8];
  }
  __syncthreads();
  {
    const int d = t >> 2, kb = (t & 3) * 16;
    const int P0[8] = {0, 1, 2, 3, 8, 9, 10, 11};
    const int P1[8] = {4, 5, 6, 7, 12, 13, 14, 15};
    bf16x8 o0, o1;
#pragma unroll
    for (int j = 0; j < 8; ++j) { o0[j] = T[kb + P0[j]][d]; o1[j] = T[kb + P1[j]][d]; }
    bf16* dst = &Vt[((size_t)((b * C_H + h) * C_DH + d)) * C_NK + kt * 64 + kb];
    *(bf16x8*)&dst[0] = o0;
    *(bf16x8*)&dst[8] = o1;
  }
}

// ---------------- Flash cross-attention: swapped-QK^T 32x32, split-K2 ----------
// Grid (NQ/128, H, 2*B): z -> {half, b}. 256 threads = 4 waves, 32 q-rows each.
// KVBLK=64 (LDS 32KB dbuf -> 4+ blocks/CU = 16 waves/CU), partial (O,m,l) out.
__global__ __launch_bounds__(256, 4) void attn_fwd(const bf16* __restrict__ Q,
                                                   const bf16* __restrict__ K,
                                                   const bf16* __restrict__ Vt,
                                                   const unsigned long long* __restrict__ MB,
                                                   bf16* __restrict__ O0,
                                                   bf16* __restrict__ O1,
                                                   float2* __restrict__ LM) {
  __shared__ __align__(16) bf16 Ks[2][64 * 64];
  __shared__ __align__(16) bf16 Vs[2][64 * 64];

  const int qt = blockIdx.x, h = blockIdx.y;
  const int half = blockIdx.z >> 1, b = blockIdx.z & 1;
  const int t = threadIdx.x, wq = t >> 6, lane = t & 63;
  const int l31 = lane & 31, hi = lane >> 5;
  const int q = qt * 128 + wq * 32 + l31;

  // Q fragments (B-operand): col=q, k-elems d = db*16 + hi*8 + j
  bf16x8 qf[4];
  {
    const bf16* qp = Q + ((size_t)(b * C_NQ + q)) * C_INNER + h * C_DH;
#pragma unroll
    for (int db = 0; db < 4; ++db)
      qf[db] = *(const bf16x8*)&qp[db * 16 + hi * 8];
  }

  float m_run = -3.0e38f, l_run = 0.f;
  f32x16 acc_o[2] = {};   // O^T: col=q, row d = d2*32 + (reg&3)+8*(reg>>2)+4*hi

  auto stage = [&](int nb, int ktA) {
#pragma unroll
    for (int i = 0; i < 2; ++i) {
      const int chunk = wq * 128 + i * 64 + lane;   // 0..511 (16B chunks)
      const int row = chunk >> 3, pcb = chunk & 7;
      const int srcb = (pcb ^ (row & 7)) * 8;       // pre-swizzled global source
      const bf16* kg = K + ((size_t)(b * C_NK + ktA * 64 + row)) * C_INNER + h * C_DH + srcb;
      async_copy16(kg, &Ks[nb][chunk * 8]);
      const bf16* vg = Vt + ((size_t)((b * C_H + h) * C_DH + row)) * C_NK + ktA * 64 + srcb;
      async_copy16(vg, &Vs[nb][chunk * 8]);
    }
  };

  const int kt0 = half * 16;          // 16 tiles of 64 keys per half
  stage(0, kt0);
  int cur = 0;

  for (int i = 0; i < 16; ++i) {
    const int ktA = kt0 + i;
    const unsigned long long wd =
        MB[((size_t)(b * C_NQ + q)) * (C_NK / 64) + ktA] >> (hi * 4);
    const unsigned mlo = (unsigned)wd, mhi = (unsigned)(wd >> 32);

    __syncthreads();                  // buf[cur] staged; prev-tile reads done
    if (i + 1 < 16) stage(cur ^ 1, ktA + 1);

    // ---- QK^T: S^T[key][q], acc per 32-key block ----
    f32x16 s[2] = {};
    __builtin_amdgcn_s_setprio(1);
#pragma unroll
    for (int kb = 0; kb < 2; ++kb)
#pragma unroll
      for (int db = 0; db < 4; ++db) {
        const int row = kb * 32 + l31;
        const int cb = (db * 2 + hi) ^ (row & 7);
        bf16x8 kf = *(const bf16x8*)&Ks[cur][row * 64 + cb * 8];
        s[kb] = __builtin_amdgcn_mfma_f32_32x32x16_bf16(kf, qf[db], s[kb], 0, 0, 0);
      }
    __builtin_amdgcn_s_setprio(0);

    // ---- row max over RAW s (safe upper bound; mask applied at exp) ----
    float pm = -1.0e30f;
#pragma unroll
    for (int kb = 0; kb < 2; ++kb)
#pragma unroll
      for (int reg = 0; reg < 16; ++reg) pm = fmaxf(pm, s[kb][reg]);
    pm = fmaxf(pm, __shfl_xor(pm, 32));

    // ---- defer-max online update: rescale only when max grows >8 ----
    if (!__all(pm <= m_run + 8.0f)) {
      const float mn = fmaxf(m_run, pm);
      const float f = EXP2(m_run - mn);
      m_run = mn;
      l_run *= f;
#pragma unroll
      for (int d2 = 0; d2 < 2; ++d2)
#pragma unroll
        for (int reg = 0; reg < 16; ++reg)
          acc_o[d2][reg] *= f;
    }

    // ---- exp2 + mask-zero + pack P (lane-local; V pre-permuted to match) ----
    bf16x8 pfr[4];
    float ps = 0.f;
#pragma unroll
    for (int kb = 0; kb < 2; ++kb) {
      const unsigned mw = kb ? mhi : mlo;
#pragma unroll
      for (int kss = 0; kss < 2; ++kss) {
        bf16x8 pf;
#pragma unroll
        for (int j = 0; j < 8; ++j) {
          const int reg = kss * 8 + j;
          const int pos = (reg & 3) + 8 * (reg >> 2);
          float p = EXP2(s[kb][reg] - m_run);
          p = ((mw >> pos) & 1u) ? p : 0.f;
          ps += p;
          pf[j] = (bf16)p;
        }
        pfr[kb * 2 + kss] = pf;
      }
    }
    l_run += ps;   // own-half (32 keys) partial; combined across hi at the end

    // ---- PV: O^T += V^T * P ----
    __builtin_amdgcn_s_setprio(1);
#pragma unroll
    for (int ks = 0; ks < 4; ++ks) {
#pragma unroll
      for (int d2 = 0; d2 < 2; ++d2) {
        const int row = d2 * 32 + l31;
        const int cb = (ks * 2 + hi) ^ (row & 7);
        bf16x8 vf = *(const bf16x8*)&Vs[cur][row * 64 + cb * 8];
        acc_o[d2] = __builtin_amdgcn_mfma_f32_32x32x16_bf16(vf, pfr[ks], acc_o[d2], 0, 0, 0);
      }
    }
    __builtin_amdgcn_s_setprio(0);
    cur ^= 1;
  }

  // ---- epilogue: store UNNORMALIZED partial O (bf16) + (m, l) ----
  {
    const float l_tot = l_run + __shfl_xor(l_run, 32);
    const size_t row = (size_t)(b * C_H + h) * C_NQ + q;
    bf16* op = (half ? O1 : O0) + row * 64;
#pragma unroll
    for (int d2 = 0; d2 < 2; ++d2)
#pragma unroll
      for (int bb = 0; bb < 4; ++bb) {
        bf16x4 o;
#pragma unroll
        for (int rr = 0; rr < 4; ++rr)
          o[rr] = (bf16)(acc_o[d2][bb * 4 + rr]);
        *(bf16x4*)&op[d2 * 32 + bb * 8 + hi * 4] = o;
      }
    if (hi == 0) LM[(size_t)half * 65536 + row] = make_float2(m_run, l_tot);
  }
}

// ---------------- merge the two K-halves ----------------
__global__ __launch_bounds__(256) void merge_halves(const bf16* __restrict__ O0,
                                                    const bf16* __restrict__ O1,
                                                    const float2* __restrict__ LM,
                                                    bf16* __restrict__ AO) {
  const int t = threadIdx.x;
  const int r = blockIdx.x * 32 + (t >> 3);   // row 0..65535 = (b*H+h)*NQ + q
  const int dc = (t & 7) * 8;
  const float2 lm0 = LM[r], lm1 = LM[65536 + r];
  const float ms = fmaxf(lm0.x, lm1.x);
  const float w0 = EXP2(lm0.x - ms), w1 = EXP2(lm1.x - ms);
  const float denom = lm0.y * w0 + lm1.y * w1;
  const float s0 = w0 / denom, s1 = w1 / denom;
  bf16x8 a = *(const bf16x8*)&O0[(size_t)r * 64 + dc];
  bf16x8 c = *(const bf16x8*)&O1[(size_t)r * 64 + dc];
  bf16x8 o;
#pragma unroll
  for (int j = 0; j < 8; ++j)
    o[j] = (bf16)((float)a[j] * s0 + (float)c[j] * s1);
  const int q = r & 2047, bh = r >> 11, hh = bh & 15, bb = bh >> 4;
  *(bf16x8*)&AO[((size_t)(bb * C_NQ + q)) * C_INNER + hh * 64 + dc] = o;
}

// ---------------- launch ----------------
extern "C" void kernel_launch(void* const* d_in, const int* in_sizes, int n_in,
                              void* d_out, int out_size, void* d_ws, size_t ws_size,
                              hipStream_t stream) {
  const float* x   = (const float*)d_in[0];
  const float* ctx = (const float*)d_in[1];
  const int*   msk = (const int*)d_in[2];
  const float* Wq  = (const float*)d_in[3];
  const float* Wk  = (const float*)d_in[4];
  const float* Wv  = (const float*)d_in[5];
  const float* Wo  = (const float*)d_in[6];
  const float* bo  = (const float*)d_in[7];
  float* out = (float*)d_out;

  // workspace layout (bf16 elems). Aliases: Vtb=xb (x dead after Q-GEMM);
  // O0 = cb..wqb region (dead after GEMMs); O1 = Vb (dead after vtrans).
  bf16* ws  = (bf16*)d_ws;
  bf16* xb  = ws;                   // 4,194,304
  bf16* cb  = xb  + 4194304;        // 3,145,728
  bf16* wqb = cb  + 3145728;        // 1,048,576
  bf16* wkb = wqb + 1048576;        //   786,432  (Wk stacked with Wv -> [2048][768])
  bf16* wvb = wkb + 786432;         //   786,432
  bf16* wob = wvb + 786432;         // 1,048,576
  bf16* Qb  = wob + 1048576;        // 4,194,304
  bf16* Kb  = Qb  + 4194304;
  bf16* Vb  = Kb  + 4194304;
  bf16* AOb = Vb  + 4194304;
  unsigned long long* mb = (unsigned long long*)(AOb + 4194304);   // 131072 u64
  float2* lm = (float2*)(mb + 131072);                             // 131072 float2
  bf16* Vtb = xb;                   // alias
  bf16* O0  = cb;                   // alias (cb+wqb = 4,194,304 elems exactly)
  bf16* O1  = Vb;                   // alias

  dim3 blk(256);
  cvt_all<<<2048, blk, 0, stream>>>(x, ctx, Wq, Wk, Wv, Wo, xb, cb, wqb, wkb, wvb, wob);

  pack_mask<<<512, blk, 0, stream>>>(msk, mb, C_B * C_NQ * (C_NK / 64));

  const int MQ = C_B * C_NQ;  // 4096
  const float qscale = 0.125f * 1.44269504f;  // DH^-0.5 * log2(e), folded into Q
  // Q projection
  gemm_bt<1, 0><<<dim3(C_INNER / 128, MQ / 128), blk, 0, stream>>>(
      xb, wqb, nullptr, Qb, MQ, C_INNER, C_QD, qscale, C_INNER, nullptr);
  // fused K|V projection: W = [Wk; Wv] (contiguous), cols >=1024 -> Vb
  gemm_bt<1, 0><<<dim3(2 * C_INNER / 128, MQ / 128), blk, 0, stream>>>(
      cb, wkb, nullptr, Kb, MQ, 2 * C_INNER, C_CD, 1.0f, C_INNER, Vb);

  vtrans<<<dim3(C_NK / 64, C_H, C_B), blk, 0, stream>>>(Vb, Vtb);

  attn_fwd<<<dim3(C_NQ / 128, C_H, 2 * C_B), blk, 0, stream>>>(
      Qb, Kb, Vtb, mb, O0, O1, lm);

  merge_halves<<<2048, blk, 0, stream>>>(O0, O1, lm, AOb);

  gemm_bt<0, 1><<<dim3(C_QD / 128, MQ / 128), blk, 0, stream>>>(
      AOb, wob, bo, out, MQ, C_QD, C_INNER, 1.0f, C_QD, nullptr);
}

// Round 9
// 152.986 us; speedup vs baseline: 6.6979x; 1.1336x over previous
//
#include <hip/hip_runtime.h>
#include <float.h>
#include <stdint.h>

#define C_B     2
#define C_NQ    2048
#define C_NK    2048
#define C_QD    1024
#define C_CD    768
#define C_H     16
#define C_DH    64
#define C_INNER 1024

typedef __bf16 bf16;
typedef __attribute__((ext_vector_type(8))) __bf16 bf16x8;
typedef __attribute__((ext_vector_type(4))) __bf16 bf16x4;
typedef __attribute__((ext_vector_type(4))) float f32x4;
typedef __attribute__((ext_vector_type(16))) float f32x16;

#if __has_builtin(__builtin_amdgcn_exp2f)
#define EXP2(x) __builtin_amdgcn_exp2f(x)
#else
#define EXP2(x) __expf((x) * 0.69314718056f)
#endif

// ---- async global->LDS, 16B per lane. LDS dest is wave-uniform base + lane*16. ----
__device__ __forceinline__ void async_copy16(const bf16* g, bf16* l) {
  __builtin_amdgcn_global_load_lds(
      (const __attribute__((address_space(1))) void*)g,
      (__attribute__((address_space(3))) void*)l,
      16, 0, 0);
}

// ---------------- prep: fused f32->bf16 converts + mask bit-pack ----------------
__global__ __launch_bounds__(256) void prep(const float* __restrict__ s0, const float* __restrict__ s1,
                                            const float* __restrict__ s2, const float* __restrict__ s3,
                                            const float* __restrict__ s4, const float* __restrict__ s5,
                                            bf16* __restrict__ d0, bf16* __restrict__ d1,
                                            bf16* __restrict__ d2, bf16* __restrict__ d3,
                                            bf16* __restrict__ d4, bf16* __restrict__ d5,
                                            const int* __restrict__ mask,
                                            unsigned long long* __restrict__ mb) {
  const int stride = gridDim.x * blockDim.x;
  for (int idx = blockIdx.x * blockDim.x + threadIdx.x; idx < 2752512; idx += stride) {
    const float* src; bf16* dst; int loc;
    if      (idx < 1048576) { src = s0; dst = d0; loc = idx; }
    else if (idx < 1835008) { src = s1; dst = d1; loc = idx - 1048576; }
    else if (idx < 2097152) { src = s2; dst = d2; loc = idx - 1835008; }
    else if (idx < 2293760) { src = s3; dst = d3; loc = idx - 2097152; }
    else if (idx < 2490368) { src = s4; dst = d4; loc = idx - 2293760; }
    else                    { src = s5; dst = d5; loc = idx - 2490368; }
    float4 f = *(const float4*)&src[loc * 4];
    bf16x4 o = { (bf16)f.x, (bf16)f.y, (bf16)f.z, (bf16)f.w };
    *(bf16x4*)&dst[loc * 4] = o;
  }
  // mask pack: one u64 per 64 keys (131072 words)
  const int lane = threadIdx.x & 63;
  const int wid  = (blockIdx.x * blockDim.x + threadIdx.x) >> 6;
  const int nw   = (gridDim.x * blockDim.x) >> 6;
  for (int w = wid; w < 131072; w += nw) {
    int v = mask[(size_t)w * 64 + lane];
    unsigned long long bb = __ballot(v != 0);
    if (lane == 0) mb[w] = bb;
  }
}

// ---------------- GEMM core: 128x128 tile, BK=32, 4 waves 2x2, dbuf, swizzled ----
__device__ __forceinline__ void gemm_core(const bf16* __restrict__ A,
                                          const bf16* __restrict__ W,
                                          int m0, int n0, int K,
                                          bf16* As0, bf16* As1, bf16* Bs0, bf16* Bs1,
                                          f32x4 (&acc)[4][4],
                                          int w, int lane) {
  const int l15 = lane & 15, lg = lane >> 4;
  const int wm = w >> 1, wn = w & 1;
  bf16* AsA[2] = {As0, As1};
  bf16* BsA[2] = {Bs0, Bs1};

  auto stage = [&](int nb, int k0) {
#pragma unroll
    for (int i = 0; i < 2; ++i) {
      const int chunk = w * 128 + i * 64 + lane;
      const int row = chunk >> 2;
      const int srcb = ((chunk & 3) ^ (row & 3)) * 8;
      async_copy16(A + (size_t)(m0 + row) * K + k0 + srcb, &AsA[nb][chunk * 8]);
      async_copy16(W + (size_t)(n0 + row) * K + k0 + srcb, &BsA[nb][chunk * 8]);
    }
  };

  stage(0, 0);
  int cur = 0;
  for (int k0 = 0; k0 < K; k0 += 32) {
    __syncthreads();
    if (k0 + 32 < K) stage(cur ^ 1, k0 + 32);

    bf16x8 af[4], bfv[4];
#pragma unroll
    for (int mi = 0; mi < 4; ++mi) {
      const int row = wm * 64 + mi * 16 + l15;
      af[mi] = *(const bf16x8*)&AsA[cur][row * 32 + ((lg ^ (row & 3)) * 8)];
    }
#pragma unroll
    for (int ni = 0; ni < 4; ++ni) {
      const int row = wn * 64 + ni * 16 + l15;
      bfv[ni] = *(const bf16x8*)&BsA[cur][row * 32 + ((lg ^ (row & 3)) * 8)];
    }
#pragma unroll
    for (int mi = 0; mi < 4; ++mi)
#pragma unroll
      for (int ni = 0; ni < 4; ++ni)
        acc[mi][ni] = __builtin_amdgcn_mfma_f32_16x16x32_bf16(af[mi], bfv[ni],
                                                              acc[mi][ni], 0, 0, 0);
    cur ^= 1;
  }
}

// ---------------- co-launched Q-proj + KV-proj (one dispatch, 768 blocks) --------
__global__ __launch_bounds__(256) void gemm_qkv(const bf16* __restrict__ xb,
                                                const bf16* __restrict__ wqb,
                                                bf16* __restrict__ Qb,
                                                const bf16* __restrict__ cb,
                                                const bf16* __restrict__ wkv,
                                                bf16* __restrict__ Kb,
                                                bf16* __restrict__ Vb,
                                                float qscale) {
  __shared__ __align__(16) bf16 As[2][128 * 32];
  __shared__ __align__(16) bf16 Bs[2][128 * 32];

  const int bid = blockIdx.x;
  const int t = threadIdx.x, w = t >> 6, lane = t & 63;
  const int l15 = lane & 15, lg = lane >> 4;
  const int wm = w >> 1, wn = w & 1;

  const bf16 *A, *W;
  int m0, n0, K, N;
  float oscale;
  if (bid < 256) {            // Q projection: N=1024, K=1024
    A = xb; W = wqb; n0 = (bid & 7) * 128; m0 = (bid >> 3) * 128;
    K = C_QD; N = C_INNER; oscale = qscale;
  } else {                    // fused K|V projection: N=2048, K=768
    const int b2 = bid - 256;
    A = cb; W = wkv; n0 = (b2 & 15) * 128; m0 = (b2 >> 4) * 128;
    K = C_CD; N = 2 * C_INNER; oscale = 1.0f;
  }

  f32x4 acc[4][4] = {};
  gemm_core(A, W, m0, n0, K, As[0], As[1], Bs[0], Bs[1], acc, w, lane);

#pragma unroll
  for (int mi = 0; mi < 4; ++mi)
#pragma unroll
    for (int ni = 0; ni < 4; ++ni)
#pragma unroll
      for (int r = 0; r < 4; ++r) {
        const int row = m0 + wm * 64 + mi * 16 + lg * 4 + r;
        const int col = n0 + wn * 64 + ni * 16 + l15;
        const float v = acc[mi][ni][r] * oscale;
        bf16* dst; int cc;
        if (bid < 256)            { dst = Qb; cc = col; }
        else if (col < C_INNER)   { dst = Kb; cc = col; }
        else                      { dst = Vb; cc = col - C_INNER; }
        dst[(size_t)row * C_INNER + cc] = (bf16)v;
      }
}

// ---------------- output projection GEMM (f32 out, +bias) ----------------
__global__ __launch_bounds__(256) void gemm_out(const bf16* __restrict__ A,
                                                const bf16* __restrict__ W,
                                                const float* __restrict__ bias,
                                                float* __restrict__ Cout,
                                                int M, int N, int K) {
  __shared__ __align__(16) bf16 As[2][128 * 32];
  __shared__ __align__(16) bf16 Bs[2][128 * 32];
  const int t = threadIdx.x, w = t >> 6, lane = t & 63;
  const int l15 = lane & 15, lg = lane >> 4;
  const int wm = w >> 1, wn = w & 1;
  const int m0 = blockIdx.y * 128, n0 = blockIdx.x * 128;

  f32x4 acc[4][4] = {};
  gemm_core(A, W, m0, n0, K, As[0], As[1], Bs[0], Bs[1], acc, w, lane);

#pragma unroll
  for (int mi = 0; mi < 4; ++mi)
#pragma unroll
    for (int ni = 0; ni < 4; ++ni)
#pragma unroll
      for (int r = 0; r < 4; ++r) {
        const int row = m0 + wm * 64 + mi * 16 + lg * 4 + r;
        const int col = n0 + wn * 64 + ni * 16 + l15;
        Cout[(size_t)row * N + col] = acc[mi][ni][r] + bias[col];
      }
}

// ---------------- V transpose + key-slot permute ----------------
__global__ __launch_bounds__(256) void vtrans(const bf16* __restrict__ V,
                                              bf16* __restrict__ Vt) {
  __shared__ __align__(16) bf16 T[64][80];
  const int kt = blockIdx.x, h = blockIdx.y, b = blockIdx.z;
  const int t = threadIdx.x;
  {
    const int kl = t >> 2, db = (t & 3) * 16;
    const bf16* src = &V[((size_t)(b * C_NK + kt * 64 + kl)) * C_INNER + h * 64 + db];
    *(bf16x8*)&T[kl][db]     = *(const bf16x8*)&src[0];
    *(bf16x8*)&T[kl][db + 8] = *(const bf16x8*)&src[8];
  }
  __syncthreads();
  {
    const int d = t >> 2, kb = (t & 3) * 16;
    const int P0[8] = {0, 1, 2, 3, 8, 9, 10, 11};
    const int P1[8] = {4, 5, 6, 7, 12, 13, 14, 15};
    bf16x8 o0, o1;
#pragma unroll
    for (int j = 0; j < 8; ++j) { o0[j] = T[kb + P0[j]][d]; o1[j] = T[kb + P1[j]][d]; }
    bf16* dst = &Vt[((size_t)((b * C_H + h) * C_DH + d)) * C_NK + kt * 64 + kb];
    *(bf16x8*)&dst[0] = o0;
    *(bf16x8*)&dst[8] = o1;
  }
}

// ---------------- Flash cross-attention: swapped-QK^T 32x32, split-K2 ----------
// Flat grid 1024, XCD-chunked swizzle: swz=(bid&7)*128+(bid>>3) -> each XCD's
// L2 holds 8 (b,h,half) K/V-groups; 16 qt-blocks per group hit that L2.
__global__ __launch_bounds__(256, 4) void attn_fwd(const bf16* __restrict__ Q,
                                                   const bf16* __restrict__ K,
                                                   const bf16* __restrict__ Vt,
                                                   const unsigned long long* __restrict__ MB,
                                                   bf16* __restrict__ O0,
                                                   bf16* __restrict__ O1,
                                                   float2* __restrict__ LM) {
  __shared__ __align__(16) bf16 Ks[2][64 * 64];
  __shared__ __align__(16) bf16 Vs[2][64 * 64];

  const int bid = blockIdx.x;
  const int swz = ((bid & 7) << 7) | (bid >> 3);   // bijective: 1024 = 8*128
  const int qt = swz & 15, h = (swz >> 4) & 15, zz = swz >> 8;
  const int half = zz >> 1, b = zz & 1;
  const int t = threadIdx.x, wq = t >> 6, lane = t & 63;
  const int l31 = lane & 31, hi = lane >> 5;
  const int q = qt * 128 + wq * 32 + l31;

  bf16x8 qf[4];
  {
    const bf16* qp = Q + ((size_t)(b * C_NQ + q)) * C_INNER + h * C_DH;
#pragma unroll
    for (int db = 0; db < 4; ++db)
      qf[db] = *(const bf16x8*)&qp[db * 16 + hi * 8];
  }

  float m_run = -3.0e38f, l_run = 0.f;
  f32x16 acc_o[2] = {};

  auto stage = [&](int nb, int ktA) {
#pragma unroll
    for (int i = 0; i < 2; ++i) {
      const int chunk = wq * 128 + i * 64 + lane;
      const int row = chunk >> 3, pcb = chunk & 7;
      const int srcb = (pcb ^ (row & 7)) * 8;
      const bf16* kg = K + ((size_t)(b * C_NK + ktA * 64 + row)) * C_INNER + h * C_DH + srcb;
      async_copy16(kg, &Ks[nb][chunk * 8]);
      const bf16* vg = Vt + ((size_t)((b * C_H + h) * C_DH + row)) * C_NK + ktA * 64 + srcb;
      async_copy16(vg, &Vs[nb][chunk * 8]);
    }
  };

  const int kt0 = half * 16;
  stage(0, kt0);
  int cur = 0;

  for (int i = 0; i < 16; ++i) {
    const int ktA = kt0 + i;
    const unsigned long long wd =
        MB[((size_t)(b * C_NQ + q)) * (C_NK / 64) + ktA] >> (hi * 4);
    const unsigned mlo = (unsigned)wd, mhi = (unsigned)(wd >> 32);

    __syncthreads();
    if (i + 1 < 16) stage(cur ^ 1, ktA + 1);

    // ---- QK^T ----
    f32x16 s[2] = {};
    __builtin_amdgcn_s_setprio(1);
#pragma unroll
    for (int kb = 0; kb < 2; ++kb)
#pragma unroll
      for (int db = 0; db < 4; ++db) {
        const int row = kb * 32 + l31;
        const int cb = (db * 2 + hi) ^ (row & 7);
        bf16x8 kf = *(const bf16x8*)&Ks[cur][row * 64 + cb * 8];
        s[kb] = __builtin_amdgcn_mfma_f32_32x32x16_bf16(kf, qf[db], s[kb], 0, 0, 0);
      }
    __builtin_amdgcn_s_setprio(0);

    // ---- row max over RAW s ----
    float pm = -1.0e30f;
#pragma unroll
    for (int kb = 0; kb < 2; ++kb)
#pragma unroll
      for (int reg = 0; reg < 16; ++reg) pm = fmaxf(pm, s[kb][reg]);
    pm = fmaxf(pm, __shfl_xor(pm, 32));

    // ---- defer-max online update ----
    if (!__all(pm <= m_run + 8.0f)) {
      const float mn = fmaxf(m_run, pm);
      const float f = EXP2(m_run - mn);
      m_run = mn;
      l_run *= f;
#pragma unroll
      for (int d2 = 0; d2 < 2; ++d2)
#pragma unroll
        for (int reg = 0; reg < 16; ++reg)
          acc_o[d2][reg] *= f;
    }

    // ---- exp2 + mask-zero + pack P ----
    bf16x8 pfr[4];
    float ps = 0.f;
#pragma unroll
    for (int kb = 0; kb < 2; ++kb) {
      const unsigned mw = kb ? mhi : mlo;
#pragma unroll
      for (int kss = 0; kss < 2; ++kss) {
        bf16x8 pf;
#pragma unroll
        for (int j = 0; j < 8; ++j) {
          const int reg = kss * 8 + j;
          const int pos = (reg & 3) + 8 * (reg >> 2);
          float p = EXP2(s[kb][reg] - m_run);
          p = ((mw >> pos) & 1u) ? p : 0.f;
          ps += p;
          pf[j] = (bf16)p;
        }
        pfr[kb * 2 + kss] = pf;
      }
    }
    l_run += ps;

    // ---- PV ----
    __builtin_amdgcn_s_setprio(1);
#pragma unroll
    for (int ks = 0; ks < 4; ++ks) {
#pragma unroll
      for (int d2 = 0; d2 < 2; ++d2) {
        const int row = d2 * 32 + l31;
        const int cb = (ks * 2 + hi) ^ (row & 7);
        bf16x8 vf = *(const bf16x8*)&Vs[cur][row * 64 + cb * 8];
        acc_o[d2] = __builtin_amdgcn_mfma_f32_32x32x16_bf16(vf, pfr[ks], acc_o[d2], 0, 0, 0);
      }
    }
    __builtin_amdgcn_s_setprio(0);
    cur ^= 1;
  }

  // ---- epilogue: store UNNORMALIZED partial O (bf16) + (m, l) ----
  {
    const float l_tot = l_run + __shfl_xor(l_run, 32);
    const size_t row = (size_t)(b * C_H + h) * C_NQ + q;
    bf16* op = (half ? O1 : O0) + row * 64;
#pragma unroll
    for (int d2 = 0; d2 < 2; ++d2)
#pragma unroll
      for (int bb = 0; bb < 4; ++bb) {
        bf16x4 o;
#pragma unroll
        for (int rr = 0; rr < 4; ++rr)
          o[rr] = (bf16)(acc_o[d2][bb * 4 + rr]);
        *(bf16x4*)&op[d2 * 32 + bb * 8 + hi * 4] = o;
      }
    if (hi == 0) LM[(size_t)half * 65536 + row] = make_float2(m_run, l_tot);
  }
}

// ---------------- merge the two K-halves ----------------
__global__ __launch_bounds__(256) void merge_halves(const bf16* __restrict__ O0,
                                                    const bf16* __restrict__ O1,
                                                    const float2* __restrict__ LM,
                                                    bf16* __restrict__ AO) {
  const int t = threadIdx.x;
  const int r = blockIdx.x * 32 + (t >> 3);
  const int dc = (t & 7) * 8;
  const float2 lm0 = LM[r], lm1 = LM[65536 + r];
  const float ms = fmaxf(lm0.x, lm1.x);
  const float w0 = EXP2(lm0.x - ms), w1 = EXP2(lm1.x - ms);
  const float denom = lm0.y * w0 + lm1.y * w1;
  const float s0 = w0 / denom, s1 = w1 / denom;
  bf16x8 a = *(const bf16x8*)&O0[(size_t)r * 64 + dc];
  bf16x8 c = *(const bf16x8*)&O1[(size_t)r * 64 + dc];
  bf16x8 o;
#pragma unroll
  for (int j = 0; j < 8; ++j)
    o[j] = (bf16)((float)a[j] * s0 + (float)c[j] * s1);
  const int q = r & 2047, bh = r >> 11, hh = bh & 15, bb = bh >> 4;
  *(bf16x8*)&AO[((size_t)(bb * C_NQ + q)) * C_INNER + hh * 64 + dc] = o;
}

// ---------------- launch ----------------
extern "C" void kernel_launch(void* const* d_in, const int* in_sizes, int n_in,
                              void* d_out, int out_size, void* d_ws, size_t ws_size,
                              hipStream_t stream) {
  const float* x   = (const float*)d_in[0];
  const float* ctx = (const float*)d_in[1];
  const int*   msk = (const int*)d_in[2];
  const float* Wq  = (const float*)d_in[3];
  const float* Wk  = (const float*)d_in[4];
  const float* Wv  = (const float*)d_in[5];
  const float* Wo  = (const float*)d_in[6];
  const float* bo  = (const float*)d_in[7];
  float* out = (float*)d_out;

  // workspace layout (bf16 elems). Aliases: Vtb=xb (x dead after Q-GEMM);
  // O0 = cb..wqb region (dead after GEMMs); O1 = Vb (dead after vtrans).
  bf16* ws  = (bf16*)d_ws;
  bf16* xb  = ws;                   // 4,194,304
  bf16* cb  = xb  + 4194304;        // 3,145,728
  bf16* wqb = cb  + 3145728;        // 1,048,576
  bf16* wkb = wqb + 1048576;        //   786,432  (Wk stacked with Wv -> [2048][768])
  bf16* wvb = wkb + 786432;         //   786,432
  bf16* wob = wvb + 786432;         // 1,048,576
  bf16* Qb  = wob + 1048576;        // 4,194,304
  bf16* Kb  = Qb  + 4194304;
  bf16* Vb  = Kb  + 4194304;
  bf16* AOb = Vb  + 4194304;
  unsigned long long* mb = (unsigned long long*)(AOb + 4194304);   // 131072 u64
  float2* lm = (float2*)(mb + 131072);                             // 131072 float2
  bf16* Vtb = xb;                   // alias
  bf16* O0  = cb;                   // alias (cb+wqb = 4,194,304 elems exactly)
  bf16* O1  = Vb;                   // alias

  dim3 blk(256);
  prep<<<2048, blk, 0, stream>>>(x, ctx, Wq, Wk, Wv, Wo,
                                 xb, cb, wqb, wkb, wvb, wob, msk, mb);

  const float qscale = 0.125f * 1.44269504f;  // DH^-0.5 * log2(e), folded into Q
  gemm_qkv<<<768, blk, 0, stream>>>(xb, wqb, Qb, cb, wkb, Kb, Vb, qscale);

  vtrans<<<dim3(C_NK / 64, C_H, C_B), blk, 0, stream>>>(Vb, Vtb);

  attn_fwd<<<1024, blk, 0, stream>>>(Qb, Kb, Vtb, mb, O0, O1, lm);

  merge_halves<<<2048, blk, 0, stream>>>(O0, O1, lm, AOb);

  const int MQ = C_B * C_NQ;  // 4096
  gemm_out<<<dim3(C_QD / 128, MQ / 128), blk, 0, stream>>>(
      AOb, wob, bo, out, MQ, C_QD, C_INNER);
}